// Round 14
// baseline (799.705 us; speedup 1.0000x reference)
//
#include <hip/hip_runtime.h>
#include <math.h>

static constexpr int N  = 50000;
static constexpr int E  = 800000;
static constexpr int F  = 64;
static constexpr int R  = 20;
static constexpr int NL = 2;
static constexpr int B  = 64;
static constexpr float RC   = 5.0f;
static constexpr float LN2F = 0.6931471805599453f;
static constexpr float WIDTH  = RC / (R - 1);
static constexpr float INV2W2 = 1.0f / (2.0f * WIDTH * WIDTH);
static constexpr float PI_F = 3.14159265358979323846f;

// filt(r) nearest-neighbor lookup table: NB intervals on [0,RC]
static constexpr int   NB     = 4096;
static constexpr float DR     = RC / NB;
static constexpr float INV_DR = NB / RC;
static constexpr int   IZERO  = NB + 1;   // all-zero entry (null/pad edges)
static constexpr int   TENTA  = NB + 2;   // entries: 0..NB real, NB+1 zero
// entry = 64 lanes x 4 ushorts {Ws, Wv, Wr, 0} = 512 B

static constexpr int NBLK_SCAN = (N + 255) / 256;  // 196

typedef __attribute__((ext_vector_type(8))) short bf16x8;
typedef __attribute__((ext_vector_type(4))) float f32x4;
typedef __attribute__((ext_vector_type(3))) unsigned uint32x3;

__device__ __forceinline__ float ssp_f(float x) {
    return fmaxf(x, 0.0f) + log1pf(__expf(-fabsf(x))) - LN2F;
}

__device__ __forceinline__ short f2bf(float x) {
    unsigned u = __builtin_bit_cast(unsigned, x);
    unsigned r = (u + 0x7fffu + ((u >> 16) & 1u)) >> 16;
    return (short)r;
}
__device__ __forceinline__ float bf_lo(unsigned u) {
    return __builtin_bit_cast(float, u << 16);
}
__device__ __forceinline__ float bf_hi(unsigned u) {
    return __builtin_bit_cast(float, u & 0xffff0000u);
}

// ---------- counting sort of edges by src, runs padded to multiple of 2 ----------
__global__ void k_hist(const int* __restrict__ ei, int* __restrict__ cnt) {
    int e = blockIdx.x * blockDim.x + threadIdx.x;
    if (e < E) atomicAdd(&cnt[ei[e]], 1);
}

__global__ void k_scan_a(const int* __restrict__ cnt, int* __restrict__ bsum) {
    __shared__ int part[256];
    const int t = threadIdx.x;
    const int idx = blockIdx.x * 256 + t;
    int v = (idx < N) ? ((cnt[idx] + 1) & ~1) : 0;   // padded count
    part[t] = v;
    __syncthreads();
    for (int d = 1; d < 256; d <<= 1) {
        int x = (t >= d) ? part[t - d] : 0;
        __syncthreads();
        part[t] += x;
        __syncthreads();
    }
    if (t == 255) bsum[blockIdx.x] = part[255];
}

__global__ void k_scan_b(const int* __restrict__ bsum, int* __restrict__ bpre,
                         int* __restrict__ offN) {
    __shared__ int part[256];
    const int t = threadIdx.x;
    int v = (t < NBLK_SCAN) ? bsum[t] : 0;
    part[t] = v;
    __syncthreads();
    for (int d = 1; d < 256; d <<= 1) {
        int x = (t >= d) ? part[t - d] : 0;
        __syncthreads();
        part[t] += x;
        __syncthreads();
    }
    if (t < NBLK_SCAN) bpre[t] = part[t] - v;   // exclusive
    if (t == NBLK_SCAN - 1) *offN = part[t];    // off[N] = padded total
}

// computes padded offsets; also writes the null pad descriptor for odd-degree nodes
__global__ void k_scan_c(const int* __restrict__ cnt, const int* __restrict__ bpre,
                         int* __restrict__ off, int* __restrict__ cur,
                         uint4* __restrict__ edata) {
    __shared__ int part[256];
    const int t = threadIdx.x;
    const int idx = blockIdx.x * 256 + t;
    int vraw = (idx < N) ? cnt[idx] : 0;
    int v = (vraw + 1) & ~1;
    part[t] = v;
    __syncthreads();
    for (int d = 1; d < 256; d <<= 1) {
        int x = (t >= d) ? part[t - d] : 0;
        __syncthreads();
        part[t] += x;
        __syncthreads();
    }
    if (idx < N) {
        int e = bpre[blockIdx.x] + part[t] - v;
        off[idx] = e;
        cur[idx] = e;
        if (vraw & 1) {
            uint4 nil;
            nil.x = (unsigned)idx * 256u;          // record byte offset (self)
            nil.y = (unsigned)IZERO * 512u;        // zero table entry byte offset
            nil.z = 0u; nil.w = 0u;
            edata[e + vraw] = nil;
        }
    }
}

// scatter one 16B record per CSR slot: {dst*256, i*512, qx|qy, qz}
__global__ void k_scatter(const int* __restrict__ ei, int* __restrict__ cur,
                          const float* __restrict__ pos, uint4* __restrict__ edata) {
    int e = blockIdx.x * blockDim.x + threadIdx.x;
    if (e >= E) return;
    int src = ei[e], dst = ei[E + e];
    int p = atomicAdd(&cur[src], 1);
    float qx = pos[dst * 3 + 0] - pos[src * 3 + 0];
    float qy = pos[dst * 3 + 1] - pos[src * 3 + 1];
    float qz = pos[dst * 3 + 2] - pos[src * 3 + 2];
    float rn = sqrtf(qx * qx + qy * qy + qz * qz);
    float invn = 1.0f / fmaxf(rn, 1e-8f);
    int i = (int)(rn * INV_DR + 0.5f);     // nearest-neighbor bin
    if (i > NB) i = NB;                    // constant region (fc = 0)
    uint4 rec;
    rec.x = (unsigned)dst * 256u;
    rec.y = (unsigned)i * 512u;
    rec.z = (unsigned)(unsigned short)f2bf(qx * invn)
          | ((unsigned)(unsigned short)f2bf(qy * invn) << 16);
    rec.w = (unsigned)(unsigned short)f2bf(qz * invn);
    edata[p] = rec;
}

// ---------- filt(r) NN table: entry i, lane: {Ws, Wv, Wr, 0} (8B/lane) ----------
__global__ void k_table(const float* __restrict__ fW1, const float* __restrict__ fb1,
                        const float* __restrict__ fW2, const float* __restrict__ fb2,
                        unsigned short* __restrict__ Tp) {
    __shared__ float sh[4][F];
    const int wid  = threadIdx.x >> 6;
    const int lane = threadIdx.x & 63;
    const int gid  = blockIdx.x * 4 + wid;          // flattened (l,row), row in [0,NB]
    if (gid >= NL * (NB + 1)) return;
    const int l   = gid / (NB + 1);
    const int row = gid % (NB + 1);
    const float r = (float)row * DR;
    const float fc = (r < RC) ? 0.5f * (__cosf(PI_F * r * (1.0f / RC)) + 1.0f) : 0.0f;

    float acc = fb1[l * F + lane];
    const float* w1 = fW1 + (size_t)l * F * R + (size_t)lane * R;
    #pragma unroll
    for (int rr = 0; rr < R; rr++) {
        float dmu = r - rr * WIDTH;
        float er = __expf(-dmu * dmu * INV2W2) * fc;
        acc = fmaf(er, w1[rr], acc);
    }
    sh[wid][lane] = ssp_f(acc);
    __syncthreads();
    unsigned short* TpL = Tp + (size_t)l * TENTA * 256;
    #pragma unroll
    for (int p = 0; p < 3; p++) {
        int c = p * 64 + lane;
        float a = fb2[l * 192 + c];
        const float* w2 = fW2 + ((size_t)l * 192 + c) * 64;
        #pragma unroll 8
        for (int k = 0; k < F; k++) a = fmaf(sh[wid][k], w2[k], a);
        TpL[(size_t)row * 256 + lane * 4 + p] = (unsigned short)f2bf(a);
    }
    TpL[(size_t)row * 256 + lane * 4 + 3] = 0;
    if (row == 0) {   // zero entry for pad edges
        #pragma unroll
        for (int j = 0; j < 4; j++)
            TpL[(size_t)IZERO * 256 + lane * 4 + j] = 0;
    }
}

// ---------- layer-0 pack: init s from emb[z], write dense ndA0 = phi_s|phi_r ----------
__launch_bounds__(256)
__global__ void k_pack0(float* __restrict__ s, const int* __restrict__ z,
                        const float* __restrict__ emb,
                        const float* __restrict__ PW, const float* __restrict__ Pb,
                        unsigned* __restrict__ ndA0) {
    __shared__ float sbuf[4][F];
    const int lane = threadIdx.x & 63;
    const int wid  = threadIdx.x >> 6;
    const int gwave = blockIdx.x * 4 + wid;
    const int nwaves = gridDim.x * 4;

    float wsr[F], wrr[F];
    {
        const float* rs = PW + (size_t)lane * 64;
        const float* rr = PW + (size_t)(128 + lane) * 64;
        #pragma unroll
        for (int k = 0; k < F; k += 4) {
            float4 a = *(const float4*)(rs + k);
            wsr[k] = a.x; wsr[k+1] = a.y; wsr[k+2] = a.z; wsr[k+3] = a.w;
            float4 b = *(const float4*)(rr + k);
            wrr[k] = b.x; wrr[k+1] = b.y; wrr[k+2] = b.z; wrr[k+3] = b.w;
        }
    }
    const float bs = Pb[lane], br = Pb[128 + lane];

    for (int n = gwave; n < N; n += nwaves) {
        float sv = emb[(size_t)z[n] * F + lane];
        s[(size_t)n * F + lane] = sv;
        sbuf[wid][lane] = sv;
        float as = bs, ar = br;
        #pragma unroll
        for (int k = 0; k < F; k += 4) {
            float4 s4 = *(const float4*)&sbuf[wid][k];
            as = fmaf(s4.x, wsr[k],   as); as = fmaf(s4.y, wsr[k+1], as);
            as = fmaf(s4.z, wsr[k+2], as); as = fmaf(s4.w, wsr[k+3], as);
            ar = fmaf(s4.x, wrr[k],   ar); ar = fmaf(s4.y, wrr[k+1], ar);
            ar = fmaf(s4.z, wrr[k+2], ar); ar = fmaf(s4.w, wrr[k+3], ar);
        }
        ndA0[(size_t)n * 64 + lane] = (unsigned)(unsigned short)f2bf(as)
                                    | ((unsigned)(unsigned short)f2bf(ar) << 16);
    }
}

// ---------- gather/message kernel: WAVE per node, 2 nodes/block ----------
template<bool ACCUMV>
__device__ __forceinline__ void consume_edge(const uint4 ed, const uint2 t,
                                             const uint32x3 r,
                                             float& ms, float& mv0, float& mv1, float& mv2) {
    const float Ws = bf_lo(t.x);
    const float Wr = bf_lo(t.y);
    ms = fmaf(Ws, bf_lo(r.x), ms);
    const float c = Wr * bf_hi(r.x);
    const float rhx = bf_lo(ed.z), rhy = bf_hi(ed.z), rhz = bf_lo(ed.w);
    if (ACCUMV) {
        const float Wv = bf_hi(t.x);
        mv0 = fmaf(Wv, bf_lo(r.y), fmaf(c, rhx, mv0));
        mv1 = fmaf(Wv, bf_hi(r.y), fmaf(c, rhy, mv1));
        mv2 = fmaf(Wv, bf_lo(r.z), fmaf(c, rhz, mv2));
    } else {
        mv0 = fmaf(c, rhx, mv0);
        mv1 = fmaf(c, rhy, mv1);
        mv2 = fmaf(c, rhz, mv2);
    }
}

template<bool ACCUMV>
__device__ __forceinline__ uint2 load_tbl(const char* __restrict__ tb, unsigned yoff) {
    return *(const uint2*)(tb + yoff);
}
template<bool ACCUMV>
__device__ __forceinline__ uint32x3 load_rec(const char* __restrict__ rb0,
                                             const char* __restrict__ rbV, unsigned xoff) {
    uint32x3 r;
    if (ACCUMV) {
        r = *(const uint32x3*)(rbV + (size_t)xoff * 3);
    } else {
        r.x = *(const unsigned*)(rb0 + xoff); r.y = 0; r.z = 0;
    }
    return r;
}

template<bool ACCUMV>
__launch_bounds__(128, 8)
__global__ void k_gather(const uint4* __restrict__ edata, const int* __restrict__ off,
                         const unsigned short* __restrict__ TpL,
                         const unsigned* __restrict__ ndA0,
                         const unsigned* __restrict__ ndAV,
                         float* __restrict__ s, float* __restrict__ v) {
    const int lane = threadIdx.x & 63;
    const int wv   = threadIdx.x >> 6;
    const int n = blockIdx.x * 2 + wv;
    if (n >= N) return;
    const int base = off[n], end = off[n + 1];   // even length

    const char* tb  = (const char*)TpL  + lane * 8;
    const char* rb0 = (const char*)ndA0 + lane * 4;
    const char* rbV = (const char*)ndAV + lane * 12;

    float ms = 0.f, mv0 = 0.f, mv1 = 0.f, mv2 = 0.f;

    if (base < end) {
        uint4 ed0 = edata[base];
        uint4 ed1 = edata[base + 1];
        uint2    t0 = load_tbl<ACCUMV>(tb, ed0.y);
        uint32x3 r0 = load_rec<ACCUMV>(rb0, rbV, ed0.x);

        for (int k = base; k < end - 2; ++k) {
            uint4 ed2 = edata[k + 2];
            uint2    t1 = load_tbl<ACCUMV>(tb, ed1.y);
            uint32x3 r1 = load_rec<ACCUMV>(rb0, rbV, ed1.x);
            consume_edge<ACCUMV>(ed0, t0, r0, ms, mv0, mv1, mv2);
            ed0 = ed1; t0 = t1; r0 = r1;
            ed1 = ed2;
        }
        // epilogue: last two edges
        uint2    t1 = load_tbl<ACCUMV>(tb, ed1.y);
        uint32x3 r1 = load_rec<ACCUMV>(rb0, rbV, ed1.x);
        consume_edge<ACCUMV>(ed0, t0, r0, ms, mv0, mv1, mv2);
        consume_edge<ACCUMV>(ed1, t1, r1, ms, mv0, mv1, mv2);
    }

    s[(size_t)n * F + lane] += ms;
    float* vo = v + (size_t)n * 3 * F + lane;
    if (ACCUMV) {
        vo[0]     += mv0;
        vo[F]     += mv1;
        vo[2 * F] += mv2;
    } else {
        vo[0] = mv0; vo[F] = mv1; vo[2 * F] = mv2;
    }
}

// ---------- MFMA node-update helpers ----------
__device__ __forceinline__ bf16x8 load_wfrag(const float* __restrict__ Wp, int ldk,
                                             int nrow, int k0) {
    const float* p = Wp + (size_t)nrow * ldk + k0;
    float4 a = *(const float4*)p;
    float4 b = *(const float4*)(p + 4);
    bf16x8 r;
    r[0] = f2bf(a.x); r[1] = f2bf(a.y); r[2] = f2bf(a.z); r[3] = f2bf(a.w);
    r[4] = f2bf(b.x); r[5] = f2bf(b.y); r[6] = f2bf(b.z); r[7] = f2bf(b.w);
    return r;
}

// ---------- layer-0 update: 64 nodes/block, writes s,v and next-layer ndAV ----------
__launch_bounds__(256)
__global__ void k_update_mfma(float* __restrict__ s, float* __restrict__ v,
                              const float* __restrict__ U_W, const float* __restrict__ V_W,
                              const float* __restrict__ aW1, const float* __restrict__ ab1,
                              const float* __restrict__ aW2, const float* __restrict__ ab2,
                              const float* __restrict__ PW, const float* __restrict__ Pb,
                              unsigned* __restrict__ ndAV) {
    __shared__ short vlds[96 * 72];
    __shared__ short xlds[32 * 136];
    __shared__ short hlds[32 * 72];

    const int tid = threadIdx.x;
    const int l   = tid & 63;
    const int w   = tid >> 6;
    const int lo  = l & 15;
    const int hi  = l >> 4;

    bf16x8 ufr[2], vfr[2], w1fr[4], w2fr[3][2];
    #pragma unroll
    for (int kk = 0; kk < 2; kk++) {
        ufr[kk] = load_wfrag(U_W, 64, w * 16 + lo, kk * 32 + hi * 8);
        vfr[kk] = load_wfrag(V_W, 64, w * 16 + lo, kk * 32 + hi * 8);
    }
    #pragma unroll
    for (int kk = 0; kk < 4; kk++)
        w1fr[kk] = load_wfrag(aW1, 128, w * 16 + lo, kk * 32 + hi * 8);
    #pragma unroll
    for (int p = 0; p < 3; p++)
        #pragma unroll
        for (int kk = 0; kk < 2; kk++)
            w2fr[p][kk] = load_wfrag(aW2, 64, p * 64 + w * 16 + lo, kk * 32 + hi * 8);

    bf16x8 pws[2], pwr[2];
    #pragma unroll
    for (int kk = 0; kk < 2; kk++) {
        pws[kk] = load_wfrag(PW, 64, w * 16 + lo, kk * 32 + hi * 8);
        pwr[kk] = load_wfrag(PW, 64, 128 + w * 16 + lo, kk * 32 + hi * 8);
    }
    const float pbs = Pb[w * 16 + lo];
    const float pbr = Pb[128 + w * 16 + lo];

    const float ab1c  = ab1[w * 16 + lo];
    const float ab2c0 = ab2[w * 16 + lo];
    const float ab2c1 = ab2[64 + w * 16 + lo];
    const float ab2c2 = ab2[128 + w * 16 + lo];
    const int g = w * 16 + lo;

    for (int half = 0; half < 2; half++) {
        const int n0 = blockIdx.x * 64 + half * 32;
        if (half) __syncthreads();

        for (int u = tid; u < 96 * 8; u += 256) {
            int row = u >> 3, oct = u & 7;
            int d = row >> 5, nn = row & 31;
            int n = min(n0 + nn, N - 1);
            const float* src = v + ((size_t)n * 3 + d) * 64 + oct * 8;
            float4 a = *(const float4*)src;
            float4 b = *(const float4*)(src + 4);
            bf16x8 t;
            t[0] = f2bf(a.x); t[1] = f2bf(a.y); t[2] = f2bf(a.z); t[3] = f2bf(a.w);
            t[4] = f2bf(b.x); t[5] = f2bf(b.y); t[6] = f2bf(b.z); t[7] = f2bf(b.w);
            *(bf16x8*)&vlds[row * 72 + oct * 8] = t;
        }
        for (int u = tid; u < 32 * 8; u += 256) {
            int nn = u >> 3, oct = u & 7;
            int n = min(n0 + nn, N - 1);
            const float* src = s + (size_t)n * 64 + oct * 8;
            float4 a = *(const float4*)src;
            float4 b = *(const float4*)(src + 4);
            bf16x8 t;
            t[0] = f2bf(a.x); t[1] = f2bf(a.y); t[2] = f2bf(a.z); t[3] = f2bf(a.w);
            t[4] = f2bf(b.x); t[5] = f2bf(b.y); t[6] = f2bf(b.z); t[7] = f2bf(b.w);
            *(bf16x8*)&xlds[nn * 136 + oct * 8] = t;
        }
        __syncthreads();

        f32x4 cu[6], cv[6];
        #pragma unroll
        for (int mt = 0; mt < 6; mt++) { cu[mt] = (f32x4)0.0f; cv[mt] = (f32x4)0.0f; }
        #pragma unroll
        for (int kk = 0; kk < 2; kk++) {
            #pragma unroll
            for (int mt = 0; mt < 6; mt++) {
                bf16x8 af = *(const bf16x8*)&vlds[(mt * 16 + lo) * 72 + kk * 32 + hi * 8];
                cu[mt] = __builtin_amdgcn_mfma_f32_16x16x32_bf16(af, ufr[kk], cu[mt], 0, 0, 0);
                cv[mt] = __builtin_amdgcn_mfma_f32_16x16x32_bf16(af, vfr[kk], cv[mt], 0, 0, 0);
            }
        }

        f32x4 inn[2];
        #pragma unroll
        for (int nt = 0; nt < 2; nt++) {
            #pragma unroll
            for (int r = 0; r < 4; r++) {
                float vs = 0.f, ii = 0.f;
                #pragma unroll
                for (int d = 0; d < 3; d++) {
                    float a = cu[d * 2 + nt][r], b = cv[d * 2 + nt][r];
                    vs = fmaf(b, b, vs);
                    ii = fmaf(a, b, ii);
                }
                inn[nt][r] = ii;
                int nl = nt * 16 + hi * 4 + r;
                xlds[nl * 136 + 64 + w * 16 + lo] = f2bf(vs);
            }
        }
        __syncthreads();

        f32x4 c2[2];
        c2[0] = (f32x4)0.0f; c2[1] = (f32x4)0.0f;
        #pragma unroll
        for (int kk = 0; kk < 4; kk++) {
            #pragma unroll
            for (int mt = 0; mt < 2; mt++) {
                bf16x8 af = *(const bf16x8*)&xlds[(mt * 16 + lo) * 136 + kk * 32 + hi * 8];
                c2[mt] = __builtin_amdgcn_mfma_f32_16x16x32_bf16(af, w1fr[kk], c2[mt], 0, 0, 0);
            }
        }
        #pragma unroll
        for (int mt = 0; mt < 2; mt++)
            #pragma unroll
            for (int r = 0; r < 4; r++) {
                float hv = ssp_f(c2[mt][r] + ab1c);
                hlds[(mt * 16 + hi * 4 + r) * 72 + w * 16 + lo] = f2bf(hv);
            }
        __syncthreads();

        f32x4 c3[2][3];
        #pragma unroll
        for (int mt = 0; mt < 2; mt++)
            #pragma unroll
            for (int p = 0; p < 3; p++) c3[mt][p] = (f32x4)0.0f;
        #pragma unroll
        for (int kk = 0; kk < 2; kk++) {
            #pragma unroll
            for (int mt = 0; mt < 2; mt++) {
                bf16x8 af = *(const bf16x8*)&hlds[(mt * 16 + lo) * 72 + kk * 32 + hi * 8];
                #pragma unroll
                for (int p = 0; p < 3; p++)
                    c3[mt][p] = __builtin_amdgcn_mfma_f32_16x16x32_bf16(af, w2fr[p][kk], c3[mt][p], 0, 0, 0);
            }
        }

        float snew[2][4];
        #pragma unroll
        for (int mt = 0; mt < 2; mt++) {
            #pragma unroll
            for (int r = 0; r < 4; r++) {
                int n = n0 + mt * 16 + hi * 4 + r;
                if (n >= N) { snew[mt][r] = 0.f; continue; }
                float a_ss = c3[mt][0][r] + ab2c0;
                float a_sv = c3[mt][1][r] + ab2c1;
                float a_vv = c3[mt][2][r] + ab2c2;
                size_t si = (size_t)n * 64 + g;
                float sn = s[si] + a_ss + a_sv * inn[mt][r];
                s[si] = sn;
                snew[mt][r] = sn;
                float vn[3];
                #pragma unroll
                for (int d = 0; d < 3; d++) {
                    size_t vi = ((size_t)n * 3 + d) * 64 + g;
                    vn[d] = v[vi] + a_vv * cu[d * 2 + mt][r];
                    v[vi] = vn[d];
                }
                unsigned* pp = ndAV + ((size_t)n * 64 + g) * 3;
                pp[1] = (unsigned)(unsigned short)f2bf(vn[0])
                      | ((unsigned)(unsigned short)f2bf(vn[1]) << 16);
                pp[2] = (unsigned)(unsigned short)f2bf(vn[2]);
            }
        }

        // pack next-layer phi via MFMA on s_new
        __syncthreads();
        #pragma unroll
        for (int mt = 0; mt < 2; mt++)
            #pragma unroll
            for (int r = 0; r < 4; r++)
                hlds[(mt * 16 + hi * 4 + r) * 72 + g] = f2bf(snew[mt][r]);
        __syncthreads();

        f32x4 cs[2], cr[2];
        cs[0] = (f32x4)0.0f; cs[1] = (f32x4)0.0f;
        cr[0] = (f32x4)0.0f; cr[1] = (f32x4)0.0f;
        #pragma unroll
        for (int kk = 0; kk < 2; kk++) {
            #pragma unroll
            for (int mt = 0; mt < 2; mt++) {
                bf16x8 af = *(const bf16x8*)&hlds[(mt * 16 + lo) * 72 + kk * 32 + hi * 8];
                cs[mt] = __builtin_amdgcn_mfma_f32_16x16x32_bf16(af, pws[kk], cs[mt], 0, 0, 0);
                cr[mt] = __builtin_amdgcn_mfma_f32_16x16x32_bf16(af, pwr[kk], cr[mt], 0, 0, 0);
            }
        }
        #pragma unroll
        for (int mt = 0; mt < 2; mt++) {
            #pragma unroll
            for (int r = 0; r < 4; r++) {
                int n = n0 + mt * 16 + hi * 4 + r;
                if (n >= N) continue;
                ndAV[((size_t)n * 64 + g) * 3] =
                      (unsigned)(unsigned short)f2bf(cs[mt][r] + pbs)
                    | ((unsigned)(unsigned short)f2bf(cr[mt][r] + pbr) << 16);
            }
        }
    }
}

// ---------- layer-1 update FUSED with heads: no s/v writeback ----------
__launch_bounds__(256)
__global__ void k_update_heads(const float* __restrict__ s, const float* __restrict__ v,
                               const float* __restrict__ U_W, const float* __restrict__ V_W,
                               const float* __restrict__ aW1, const float* __restrict__ ab1,
                               const float* __restrict__ aW2, const float* __restrict__ ab2,
                               const float* __restrict__ eW1, const float* __restrict__ eb1,
                               const float* __restrict__ eW2, const float* __restrict__ eb2,
                               const float* __restrict__ dip_w,
                               const int* __restrict__ bidx,
                               float* __restrict__ eacc, float* __restrict__ macc) {
    __shared__ short vlds[96 * 72];
    __shared__ short xlds[32 * 136];
    __shared__ short hlds[32 * 72];
    __shared__ float epsb[2][2][16];        // [node-half][col-half][node-in-16]
    __shared__ float dmub[4][2][16][3];     // [wave][mt][node-in-16][d]

    const int tid = threadIdx.x;
    const int l   = tid & 63;
    const int w   = tid >> 6;
    const int lo  = l & 15;
    const int hi  = l >> 4;

    bf16x8 ufr[2], vfr[2], w1fr[4], w2fr[3][2], e1fr[2];
    #pragma unroll
    for (int kk = 0; kk < 2; kk++) {
        ufr[kk] = load_wfrag(U_W, 64, w * 16 + lo, kk * 32 + hi * 8);
        vfr[kk] = load_wfrag(V_W, 64, w * 16 + lo, kk * 32 + hi * 8);
        e1fr[kk] = load_wfrag(eW1, 64, (w & 1) * 16 + lo, kk * 32 + hi * 8);
    }
    #pragma unroll
    for (int kk = 0; kk < 4; kk++)
        w1fr[kk] = load_wfrag(aW1, 128, w * 16 + lo, kk * 32 + hi * 8);
    #pragma unroll
    for (int p = 0; p < 3; p++)
        #pragma unroll
        for (int kk = 0; kk < 2; kk++)
            w2fr[p][kk] = load_wfrag(aW2, 64, p * 64 + w * 16 + lo, kk * 32 + hi * 8);

    const float ab1c  = ab1[w * 16 + lo];
    const float ab2c0 = ab2[w * 16 + lo];
    const float ab2c1 = ab2[64 + w * 16 + lo];
    const float ab2c2 = ab2[128 + w * 16 + lo];
    const float eb1v  = eb1[(w & 1) * 16 + lo];
    const float ew2v  = eW2[(w & 1) * 16 + lo];
    const float eb2c  = eb2[0];
    const int g = w * 16 + lo;
    const float dwv = dip_w[g];

    for (int half = 0; half < 2; half++) {
        const int n0 = blockIdx.x * 64 + half * 32;
        if (half) __syncthreads();

        for (int u = tid; u < 96 * 8; u += 256) {
            int row = u >> 3, oct = u & 7;
            int d = row >> 5, nn = row & 31;
            int n = min(n0 + nn, N - 1);
            const float* src = v + ((size_t)n * 3 + d) * 64 + oct * 8;
            float4 a = *(const float4*)src;
            float4 b = *(const float4*)(src + 4);
            bf16x8 t;
            t[0] = f2bf(a.x); t[1] = f2bf(a.y); t[2] = f2bf(a.z); t[3] = f2bf(a.w);
            t[4] = f2bf(b.x); t[5] = f2bf(b.y); t[6] = f2bf(b.z); t[7] = f2bf(b.w);
            *(bf16x8*)&vlds[row * 72 + oct * 8] = t;
        }
        for (int u = tid; u < 32 * 8; u += 256) {
            int nn = u >> 3, oct = u & 7;
            int n = min(n0 + nn, N - 1);
            const float* src = s + (size_t)n * 64 + oct * 8;
            float4 a = *(const float4*)src;
            float4 b = *(const float4*)(src + 4);
            bf16x8 t;
            t[0] = f2bf(a.x); t[1] = f2bf(a.y); t[2] = f2bf(a.z); t[3] = f2bf(a.w);
            t[4] = f2bf(b.x); t[5] = f2bf(b.y); t[6] = f2bf(b.z); t[7] = f2bf(b.w);
            *(bf16x8*)&xlds[nn * 136 + oct * 8] = t;
        }
        __syncthreads();

        f32x4 cu[6], cv[6];
        #pragma unroll
        for (int mt = 0; mt < 6; mt++) { cu[mt] = (f32x4)0.0f; cv[mt] = (f32x4)0.0f; }
        #pragma unroll
        for (int kk = 0; kk < 2; kk++) {
            #pragma unroll
            for (int mt = 0; mt < 6; mt++) {
                bf16x8 af = *(const bf16x8*)&vlds[(mt * 16 + lo) * 72 + kk * 32 + hi * 8];
                cu[mt] = __builtin_amdgcn_mfma_f32_16x16x32_bf16(af, ufr[kk], cu[mt], 0, 0, 0);
                cv[mt] = __builtin_amdgcn_mfma_f32_16x16x32_bf16(af, vfr[kk], cv[mt], 0, 0, 0);
            }
        }

        f32x4 inn[2];
        #pragma unroll
        for (int nt = 0; nt < 2; nt++) {
            #pragma unroll
            for (int r = 0; r < 4; r++) {
                float vs = 0.f, ii = 0.f;
                #pragma unroll
                for (int d = 0; d < 3; d++) {
                    float a = cu[d * 2 + nt][r], b = cv[d * 2 + nt][r];
                    vs = fmaf(b, b, vs);
                    ii = fmaf(a, b, ii);
                }
                inn[nt][r] = ii;
                int nl = nt * 16 + hi * 4 + r;
                xlds[nl * 136 + 64 + w * 16 + lo] = f2bf(vs);
            }
        }
        __syncthreads();

        f32x4 c2[2];
        c2[0] = (f32x4)0.0f; c2[1] = (f32x4)0.0f;
        #pragma unroll
        for (int kk = 0; kk < 4; kk++) {
            #pragma unroll
            for (int mt = 0; mt < 2; mt++) {
                bf16x8 af = *(const bf16x8*)&xlds[(mt * 16 + lo) * 136 + kk * 32 + hi * 8];
                c2[mt] = __builtin_amdgcn_mfma_f32_16x16x32_bf16(af, w1fr[kk], c2[mt], 0, 0, 0);
            }
        }
        #pragma unroll
        for (int mt = 0; mt < 2; mt++)
            #pragma unroll
            for (int r = 0; r < 4; r++) {
                float hv = ssp_f(c2[mt][r] + ab1c);
                hlds[(mt * 16 + hi * 4 + r) * 72 + w * 16 + lo] = f2bf(hv);
            }
        __syncthreads();

        f32x4 c3[2][3];
        #pragma unroll
        for (int mt = 0; mt < 2; mt++)
            #pragma unroll
            for (int p = 0; p < 3; p++) c3[mt][p] = (f32x4)0.0f;
        #pragma unroll
        for (int kk = 0; kk < 2; kk++) {
            #pragma unroll
            for (int mt = 0; mt < 2; mt++) {
                bf16x8 af = *(const bf16x8*)&hlds[(mt * 16 + lo) * 72 + kk * 32 + hi * 8];
                #pragma unroll
                for (int p = 0; p < 3; p++)
                    c3[mt][p] = __builtin_amdgcn_mfma_f32_16x16x32_bf16(af, w2fr[p][kk], c3[mt][p], 0, 0, 0);
            }
        }

        // epilogue: s_new/v_new kept in registers only (no global writeback)
        float snew[2][4];
        float vnk[2][4][3];
        #pragma unroll
        for (int mt = 0; mt < 2; mt++) {
            #pragma unroll
            for (int r = 0; r < 4; r++) {
                int n = n0 + mt * 16 + hi * 4 + r;
                if (n >= N) {
                    snew[mt][r] = 0.f;
                    vnk[mt][r][0] = vnk[mt][r][1] = vnk[mt][r][2] = 0.f;
                    continue;
                }
                float a_ss = c3[mt][0][r] + ab2c0;
                float a_sv = c3[mt][1][r] + ab2c1;
                float a_vv = c3[mt][2][r] + ab2c2;
                size_t si = (size_t)n * 64 + g;
                snew[mt][r] = s[si] + a_ss + a_sv * inn[mt][r];
                #pragma unroll
                for (int d = 0; d < 3; d++) {
                    size_t vi = ((size_t)n * 3 + d) * 64 + g;
                    vnk[mt][r][d] = v[vi] + a_vv * cu[d * 2 + mt][r];
                }
            }
        }

        // ---- heads: eps via MFMA on s_new ----
        __syncthreads();   // hlds free (GEMM3 done by all waves)
        #pragma unroll
        for (int mt = 0; mt < 2; mt++)
            #pragma unroll
            for (int r = 0; r < 4; r++)
                hlds[(mt * 16 + hi * 4 + r) * 72 + g] = f2bf(snew[mt][r]);
        __syncthreads();

        {
            const int a2 = w >> 1;
            f32x4 cx = (f32x4)0.0f;
            #pragma unroll
            for (int kk = 0; kk < 2; kk++) {
                bf16x8 af = *(const bf16x8*)&hlds[(a2 * 16 + lo) * 72 + kk * 32 + hi * 8];
                cx = __builtin_amdgcn_mfma_f32_16x16x32_bf16(af, e1fr[kk], cx, 0, 0, 0);
            }
            float part[4];
            #pragma unroll
            for (int r = 0; r < 4; r++)
                part[r] = ssp_f(cx[r] + eb1v) * ew2v;
            #pragma unroll
            for (int m2 = 1; m2 < 16; m2 <<= 1)
                #pragma unroll
                for (int r = 0; r < 4; r++)
                    part[r] += __shfl_xor(part[r], m2);
            if (lo == 0)
                #pragma unroll
                for (int r = 0; r < 4; r++)
                    epsb[a2][w & 1][hi * 4 + r] = part[r];
        }

        // ---- heads: dipole partials from v_new registers ----
        #pragma unroll
        for (int mt = 0; mt < 2; mt++)
            #pragma unroll
            for (int r = 0; r < 4; r++)
                #pragma unroll
                for (int d = 0; d < 3; d++) {
                    float val = dwv * vnk[mt][r][d];
                    #pragma unroll
                    for (int m2 = 1; m2 < 16; m2 <<= 1)
                        val += __shfl_xor(val, m2);
                    if (lo == 0) dmub[w][mt][hi * 4 + r][d] = val;
                }
        __syncthreads();

        // ---- combine + global atomics ----
        if (tid < 32) {
            int nn = tid, a2 = nn >> 4, idx = nn & 15;
            int n = n0 + nn;
            if (n < N) {
                float ev = epsb[a2][0][idx] + epsb[a2][1][idx] + eb2c;
                atomicAdd(&eacc[bidx[n]], ev);
            }
        } else if (tid >= 64 && tid < 160) {
            int t2 = tid - 64;
            int nn = t2 / 3, d = t2 % 3;
            int n = n0 + nn;
            if (n < N) {
                float mv = dmub[0][nn >> 4][nn & 15][d] + dmub[1][nn >> 4][nn & 15][d]
                         + dmub[2][nn >> 4][nn & 15][d] + dmub[3][nn >> 4][nn & 15][d];
                atomicAdd(&macc[d * B + bidx[n]], mv);
            }
        }
    }
}

__global__ void k_final(const float* __restrict__ eacc, const float* __restrict__ macc,
                        float* __restrict__ out) {
    int b = threadIdx.x;
    if (b < B) {
        out[b] = eacc[b];
        float mx = macc[b], my = macc[B + b], mz = macc[2 * B + b];
        out[B + b] = sqrtf(mx * mx + my * my + mz * mz);
    }
}

extern "C" void kernel_launch(void* const* d_in, const int* in_sizes, int n_in,
                              void* d_out, int out_size, void* d_ws, size_t ws_size,
                              hipStream_t stream) {
    const int*   z     = (const int*)d_in[0];
    const float* pos   = (const float*)d_in[1];
    const int*   ei    = (const int*)d_in[2];
    const int*   bidx  = (const int*)d_in[3];
    const float* emb   = (const float*)d_in[4];
    const float* phi_W = (const float*)d_in[5];
    const float* phi_b = (const float*)d_in[6];
    const float* fW1   = (const float*)d_in[7];
    const float* fb1   = (const float*)d_in[8];
    const float* fW2   = (const float*)d_in[9];
    const float* fb2   = (const float*)d_in[10];
    const float* U_W   = (const float*)d_in[11];
    const float* V_W   = (const float*)d_in[12];
    const float* aW1   = (const float*)d_in[13];
    const float* ab1   = (const float*)d_in[14];
    const float* aW2   = (const float*)d_in[15];
    const float* ab2   = (const float*)d_in[16];
    const float* eW1   = (const float*)d_in[17];
    const float* eb1   = (const float*)d_in[18];
    const float* eW2   = (const float*)d_in[19];
    const float* eb2   = (const float*)d_in[20];
    const float* dip_w = (const float*)d_in[21];
    float* out = (float*)d_out;

    // ---- workspace carve-up ----
    float* ws = (float*)d_ws;
    float* s    = ws;                                  // N*64 f32
    float* v    = s + (size_t)N * F;                   // N*192 f32
    unsigned* ndA0 = (unsigned*)(v + (size_t)N * F * 3);  // N*64 uint (L0 record)
    unsigned* ndAV = ndA0 + (size_t)N * 64;            // N*64*3 uint (L1 fused record)
    unsigned short* Tp = (unsigned short*)(ndAV + (size_t)N * 64 * 3); // NL*TENTA*256 u16
    float* eacc = (float*)(Tp + (size_t)NL * TENTA * 256); // B
    float* macc = eacc + B;                            // 3B
    int*   cnt  = (int*)(macc + 3 * B);                // N
    int*   off  = cnt  + N;                            // N+1
    int*   cur  = off  + N + 1;                        // N
    int*   bsum = cur  + N;                            // 256
    int*   bpre = bsum + 256;                          // 256
    uint4* edata = (uint4*)(((uintptr_t)(bpre + 256) + 15) & ~(uintptr_t)15); // (E+N)*16B

    hipMemsetAsync(cnt,  0, sizeof(int) * N, stream);
    hipMemsetAsync(eacc, 0, sizeof(float) * 4 * B, stream);
    hipMemsetAsync(out + 2 * B, 0, sizeof(float) * (size_t)N, stream); // charges

    k_hist<<<(E + 255) / 256, 256, 0, stream>>>(ei, cnt);
    k_scan_a<<<NBLK_SCAN, 256, 0, stream>>>(cnt, bsum);
    k_scan_b<<<1, 256, 0, stream>>>(bsum, bpre, off + N);
    k_scan_c<<<NBLK_SCAN, 256, 0, stream>>>(cnt, bpre, off, cur, edata);
    k_scatter<<<(E + 255) / 256, 256, 0, stream>>>(ei, cur, pos, edata);
    k_table<<<(NL * (NB + 1) + 3) / 4, 256, 0, stream>>>(fW1, fb1, fW2, fb2, Tp);

    const int gblocks = (N + 1) / 2;
    const int ublocks = (N + 63) / 64;
    // layer 0
    k_pack0<<<512, 256, 0, stream>>>(s, z, emb, phi_W, phi_b, ndA0);
    k_gather<false><<<gblocks, 128, 0, stream>>>(edata, off, Tp, ndA0, ndAV, s, v);
    k_update_mfma<<<ublocks, 256, 0, stream>>>(s, v,
        U_W, V_W, aW1, ab1, aW2, ab2,
        phi_W + (size_t)192 * 64, phi_b + 192, ndAV);
    // layer 1 (update fused with heads; no s/v writeback)
    k_gather<true><<<gblocks, 128, 0, stream>>>(edata, off,
        Tp + (size_t)TENTA * 256, ndA0, ndAV, s, v);
    k_update_heads<<<ublocks, 256, 0, stream>>>(s, v,
        U_W + 4096, V_W + 4096, aW1 + 8192, ab1 + F, aW2 + 12288, ab2 + 192,
        eW1, eb1, eW2, eb2, dip_w, bidx, eacc, macc);

    k_final<<<1, 64, 0, stream>>>(eacc, macc, out);
}

// Round 15
// 477.546 us; speedup vs baseline: 1.6746x; 1.6746x over previous
//
#include <hip/hip_runtime.h>
#include <math.h>

static constexpr int N  = 50000;
static constexpr int E  = 800000;
static constexpr int F  = 64;
static constexpr int R  = 20;
static constexpr int NL = 2;
static constexpr int B  = 64;
static constexpr float RC   = 5.0f;
static constexpr float LN2F = 0.6931471805599453f;
static constexpr float WIDTH  = RC / (R - 1);
static constexpr float INV2W2 = 1.0f / (2.0f * WIDTH * WIDTH);
static constexpr float PI_F = 3.14159265358979323846f;

// filt(r) nearest-neighbor lookup table: NB intervals on [0,RC]
static constexpr int   NB     = 4096;
static constexpr float DR     = RC / NB;
static constexpr float INV_DR = NB / RC;
static constexpr int   IZERO  = NB + 1;   // all-zero entry (null/pad edges)
static constexpr int   TENTA  = NB + 2;   // entries: 0..NB real, NB+1 zero
// entry = 64 lanes x 4 ushorts {Ws, Wv, Wr, 0} = 512 B

static constexpr int NBLK_SCAN = (N + 255) / 256;  // 196

typedef __attribute__((ext_vector_type(8))) short bf16x8;
typedef __attribute__((ext_vector_type(4))) float f32x4;
typedef __attribute__((ext_vector_type(3))) unsigned uint32x3;

__device__ __forceinline__ float ssp_f(float x) {
    return fmaxf(x, 0.0f) + log1pf(__expf(-fabsf(x))) - LN2F;
}

__device__ __forceinline__ short f2bf(float x) {
    unsigned u = __builtin_bit_cast(unsigned, x);
    unsigned r = (u + 0x7fffu + ((u >> 16) & 1u)) >> 16;
    return (short)r;
}
__device__ __forceinline__ float bf_lo(unsigned u) {
    return __builtin_bit_cast(float, u << 16);
}
__device__ __forceinline__ float bf_hi(unsigned u) {
    return __builtin_bit_cast(float, u & 0xffff0000u);
}

// ---------- counting sort of edges by src, runs padded to multiple of 2 ----------
__global__ void k_hist(const int* __restrict__ ei, int* __restrict__ cnt) {
    int e = blockIdx.x * blockDim.x + threadIdx.x;
    if (e < E) atomicAdd(&cnt[ei[e]], 1);
}

__global__ void k_scan_a(const int* __restrict__ cnt, int* __restrict__ bsum) {
    __shared__ int part[256];
    const int t = threadIdx.x;
    const int idx = blockIdx.x * 256 + t;
    int v = (idx < N) ? ((cnt[idx] + 1) & ~1) : 0;   // padded count
    part[t] = v;
    __syncthreads();
    for (int d = 1; d < 256; d <<= 1) {
        int x = (t >= d) ? part[t - d] : 0;
        __syncthreads();
        part[t] += x;
        __syncthreads();
    }
    if (t == 255) bsum[blockIdx.x] = part[255];
}

__global__ void k_scan_b(const int* __restrict__ bsum, int* __restrict__ bpre,
                         int* __restrict__ offN) {
    __shared__ int part[256];
    const int t = threadIdx.x;
    int v = (t < NBLK_SCAN) ? bsum[t] : 0;
    part[t] = v;
    __syncthreads();
    for (int d = 1; d < 256; d <<= 1) {
        int x = (t >= d) ? part[t - d] : 0;
        __syncthreads();
        part[t] += x;
        __syncthreads();
    }
    if (t < NBLK_SCAN) bpre[t] = part[t] - v;   // exclusive
    if (t == NBLK_SCAN - 1) *offN = part[t];    // off[N] = padded total
}

// computes padded offsets; also writes the null pad descriptor for odd-degree nodes
__global__ void k_scan_c(const int* __restrict__ cnt, const int* __restrict__ bpre,
                         int* __restrict__ off, int* __restrict__ cur,
                         uint4* __restrict__ edata) {
    __shared__ int part[256];
    const int t = threadIdx.x;
    const int idx = blockIdx.x * 256 + t;
    int vraw = (idx < N) ? cnt[idx] : 0;
    int v = (vraw + 1) & ~1;
    part[t] = v;
    __syncthreads();
    for (int d = 1; d < 256; d <<= 1) {
        int x = (t >= d) ? part[t - d] : 0;
        __syncthreads();
        part[t] += x;
        __syncthreads();
    }
    if (idx < N) {
        int e = bpre[blockIdx.x] + part[t] - v;
        off[idx] = e;
        cur[idx] = e;
        if (vraw & 1) {
            uint4 nil;
            nil.x = (unsigned)idx * 256u;          // record byte offset (self)
            nil.y = (unsigned)IZERO * 512u;        // zero table entry byte offset
            nil.z = 0u; nil.w = 0u;
            edata[e + vraw] = nil;
        }
    }
}

// scatter one 16B record per CSR slot: {dst*256, i*512, qx|qy, qz}
__global__ void k_scatter(const int* __restrict__ ei, int* __restrict__ cur,
                          const float* __restrict__ pos, uint4* __restrict__ edata) {
    int e = blockIdx.x * blockDim.x + threadIdx.x;
    if (e >= E) return;
    int src = ei[e], dst = ei[E + e];
    int p = atomicAdd(&cur[src], 1);
    float qx = pos[dst * 3 + 0] - pos[src * 3 + 0];
    float qy = pos[dst * 3 + 1] - pos[src * 3 + 1];
    float qz = pos[dst * 3 + 2] - pos[src * 3 + 2];
    float rn = sqrtf(qx * qx + qy * qy + qz * qz);
    float invn = 1.0f / fmaxf(rn, 1e-8f);
    int i = (int)(rn * INV_DR + 0.5f);     // nearest-neighbor bin
    if (i > NB) i = NB;                    // constant region (fc = 0)
    uint4 rec;
    rec.x = (unsigned)dst * 256u;
    rec.y = (unsigned)i * 512u;
    rec.z = (unsigned)(unsigned short)f2bf(qx * invn)
          | ((unsigned)(unsigned short)f2bf(qy * invn) << 16);
    rec.w = (unsigned)(unsigned short)f2bf(qz * invn);
    edata[p] = rec;
}

// ---------- filt(r) NN table: entry i, lane: {Ws, Wv, Wr, 0} (8B/lane) ----------
__global__ void k_table(const float* __restrict__ fW1, const float* __restrict__ fb1,
                        const float* __restrict__ fW2, const float* __restrict__ fb2,
                        unsigned short* __restrict__ Tp) {
    __shared__ float sh[4][F];
    const int wid  = threadIdx.x >> 6;
    const int lane = threadIdx.x & 63;
    const int gid  = blockIdx.x * 4 + wid;          // flattened (l,row), row in [0,NB]
    if (gid >= NL * (NB + 1)) return;
    const int l   = gid / (NB + 1);
    const int row = gid % (NB + 1);
    const float r = (float)row * DR;
    const float fc = (r < RC) ? 0.5f * (__cosf(PI_F * r * (1.0f / RC)) + 1.0f) : 0.0f;

    float acc = fb1[l * F + lane];
    const float* w1 = fW1 + (size_t)l * F * R + (size_t)lane * R;
    #pragma unroll
    for (int rr = 0; rr < R; rr++) {
        float dmu = r - rr * WIDTH;
        float er = __expf(-dmu * dmu * INV2W2) * fc;
        acc = fmaf(er, w1[rr], acc);
    }
    sh[wid][lane] = ssp_f(acc);
    __syncthreads();
    unsigned short* TpL = Tp + (size_t)l * TENTA * 256;
    #pragma unroll
    for (int p = 0; p < 3; p++) {
        int c = p * 64 + lane;
        float a = fb2[l * 192 + c];
        const float* w2 = fW2 + ((size_t)l * 192 + c) * 64;
        #pragma unroll 8
        for (int k = 0; k < F; k++) a = fmaf(sh[wid][k], w2[k], a);
        TpL[(size_t)row * 256 + lane * 4 + p] = (unsigned short)f2bf(a);
    }
    TpL[(size_t)row * 256 + lane * 4 + 3] = 0;
    if (row == 0) {   // zero entry for pad edges
        #pragma unroll
        for (int j = 0; j < 4; j++)
            TpL[(size_t)IZERO * 256 + lane * 4 + j] = 0;
    }
}

// ---------- layer-0 pack: init s from emb[z], write dense ndA0 = phi_s|phi_r ----------
__launch_bounds__(256)
__global__ void k_pack0(float* __restrict__ s, const int* __restrict__ z,
                        const float* __restrict__ emb,
                        const float* __restrict__ PW, const float* __restrict__ Pb,
                        unsigned* __restrict__ ndA0) {
    __shared__ float sbuf[4][F];
    const int lane = threadIdx.x & 63;
    const int wid  = threadIdx.x >> 6;
    const int gwave = blockIdx.x * 4 + wid;
    const int nwaves = gridDim.x * 4;

    float wsr[F], wrr[F];
    {
        const float* rs = PW + (size_t)lane * 64;
        const float* rr = PW + (size_t)(128 + lane) * 64;
        #pragma unroll
        for (int k = 0; k < F; k += 4) {
            float4 a = *(const float4*)(rs + k);
            wsr[k] = a.x; wsr[k+1] = a.y; wsr[k+2] = a.z; wsr[k+3] = a.w;
            float4 b = *(const float4*)(rr + k);
            wrr[k] = b.x; wrr[k+1] = b.y; wrr[k+2] = b.z; wrr[k+3] = b.w;
        }
    }
    const float bs = Pb[lane], br = Pb[128 + lane];

    for (int n = gwave; n < N; n += nwaves) {
        float sv = emb[(size_t)z[n] * F + lane];
        s[(size_t)n * F + lane] = sv;
        sbuf[wid][lane] = sv;
        float as = bs, ar = br;
        #pragma unroll
        for (int k = 0; k < F; k += 4) {
            float4 s4 = *(const float4*)&sbuf[wid][k];
            as = fmaf(s4.x, wsr[k],   as); as = fmaf(s4.y, wsr[k+1], as);
            as = fmaf(s4.z, wsr[k+2], as); as = fmaf(s4.w, wsr[k+3], as);
            ar = fmaf(s4.x, wrr[k],   ar); ar = fmaf(s4.y, wrr[k+1], ar);
            ar = fmaf(s4.z, wrr[k+2], ar); ar = fmaf(s4.w, wrr[k+3], ar);
        }
        ndA0[(size_t)n * 64 + lane] = (unsigned)(unsigned short)f2bf(as)
                                    | ((unsigned)(unsigned short)f2bf(ar) << 16);
    }
}

// ---------- gather/message kernel: WAVE per node, 2 nodes/block ----------
template<bool ACCUMV>
__device__ __forceinline__ void consume_edge(const uint4 ed, const uint2 t,
                                             const uint32x3 r,
                                             float& ms, float& mv0, float& mv1, float& mv2) {
    const float Ws = bf_lo(t.x);
    const float Wr = bf_lo(t.y);
    ms = fmaf(Ws, bf_lo(r.x), ms);
    const float c = Wr * bf_hi(r.x);
    const float rhx = bf_lo(ed.z), rhy = bf_hi(ed.z), rhz = bf_lo(ed.w);
    if (ACCUMV) {
        const float Wv = bf_hi(t.x);
        mv0 = fmaf(Wv, bf_lo(r.y), fmaf(c, rhx, mv0));
        mv1 = fmaf(Wv, bf_hi(r.y), fmaf(c, rhy, mv1));
        mv2 = fmaf(Wv, bf_lo(r.z), fmaf(c, rhz, mv2));
    } else {
        mv0 = fmaf(c, rhx, mv0);
        mv1 = fmaf(c, rhy, mv1);
        mv2 = fmaf(c, rhz, mv2);
    }
}

template<bool ACCUMV>
__device__ __forceinline__ uint2 load_tbl(const char* __restrict__ tb, unsigned yoff) {
    return *(const uint2*)(tb + yoff);
}
template<bool ACCUMV>
__device__ __forceinline__ uint32x3 load_rec(const char* __restrict__ rb0,
                                             const char* __restrict__ rbV, unsigned xoff) {
    uint32x3 r;
    if (ACCUMV) {
        r = *(const uint32x3*)(rbV + (size_t)xoff * 3);
    } else {
        r.x = *(const unsigned*)(rb0 + xoff); r.y = 0; r.z = 0;
    }
    return r;
}

template<bool ACCUMV>
__launch_bounds__(128, 8)
__global__ void k_gather(const uint4* __restrict__ edata, const int* __restrict__ off,
                         const unsigned short* __restrict__ TpL,
                         const unsigned* __restrict__ ndA0,
                         const unsigned* __restrict__ ndAV,
                         float* __restrict__ s, float* __restrict__ v) {
    const int lane = threadIdx.x & 63;
    const int wv   = threadIdx.x >> 6;
    const int n = blockIdx.x * 2 + wv;
    if (n >= N) return;
    const int base = off[n], end = off[n + 1];   // even length

    const char* tb  = (const char*)TpL  + lane * 8;
    const char* rb0 = (const char*)ndA0 + lane * 4;
    const char* rbV = (const char*)ndAV + lane * 12;

    float ms = 0.f, mv0 = 0.f, mv1 = 0.f, mv2 = 0.f;

    if (base < end) {
        uint4 ed0 = edata[base];
        uint4 ed1 = edata[base + 1];
        uint2    t0 = load_tbl<ACCUMV>(tb, ed0.y);
        uint32x3 r0 = load_rec<ACCUMV>(rb0, rbV, ed0.x);

        for (int k = base; k < end - 2; ++k) {
            uint4 ed2 = edata[k + 2];
            uint2    t1 = load_tbl<ACCUMV>(tb, ed1.y);
            uint32x3 r1 = load_rec<ACCUMV>(rb0, rbV, ed1.x);
            consume_edge<ACCUMV>(ed0, t0, r0, ms, mv0, mv1, mv2);
            ed0 = ed1; t0 = t1; r0 = r1;
            ed1 = ed2;
        }
        // epilogue: last two edges
        uint2    t1 = load_tbl<ACCUMV>(tb, ed1.y);
        uint32x3 r1 = load_rec<ACCUMV>(rb0, rbV, ed1.x);
        consume_edge<ACCUMV>(ed0, t0, r0, ms, mv0, mv1, mv2);
        consume_edge<ACCUMV>(ed1, t1, r1, ms, mv0, mv1, mv2);
    }

    s[(size_t)n * F + lane] += ms;
    float* vo = v + (size_t)n * 3 * F + lane;
    if (ACCUMV) {
        vo[0]     += mv0;
        vo[F]     += mv1;
        vo[2 * F] += mv2;
    } else {
        vo[0] = mv0; vo[F] = mv1; vo[2 * F] = mv2;
    }
}

// ---------- MFMA node-update helpers ----------
__device__ __forceinline__ bf16x8 load_wfrag(const float* __restrict__ Wp, int ldk,
                                             int nrow, int k0) {
    const float* p = Wp + (size_t)nrow * ldk + k0;
    float4 a = *(const float4*)p;
    float4 b = *(const float4*)(p + 4);
    bf16x8 r;
    r[0] = f2bf(a.x); r[1] = f2bf(a.y); r[2] = f2bf(a.z); r[3] = f2bf(a.w);
    r[4] = f2bf(b.x); r[5] = f2bf(b.y); r[6] = f2bf(b.z); r[7] = f2bf(b.w);
    return r;
}

// ---------- layer-0 update: 64 nodes/block, writes s,v and next-layer ndAV ----------
__launch_bounds__(256)
__global__ void k_update_mfma(float* __restrict__ s, float* __restrict__ v,
                              const float* __restrict__ U_W, const float* __restrict__ V_W,
                              const float* __restrict__ aW1, const float* __restrict__ ab1,
                              const float* __restrict__ aW2, const float* __restrict__ ab2,
                              const float* __restrict__ PW, const float* __restrict__ Pb,
                              unsigned* __restrict__ ndAV) {
    __shared__ short vlds[96 * 72];
    __shared__ short xlds[32 * 136];
    __shared__ short hlds[32 * 72];

    const int tid = threadIdx.x;
    const int l   = tid & 63;
    const int w   = tid >> 6;
    const int lo  = l & 15;
    const int hi  = l >> 4;

    bf16x8 ufr[2], vfr[2], w1fr[4], w2fr[3][2];
    #pragma unroll
    for (int kk = 0; kk < 2; kk++) {
        ufr[kk] = load_wfrag(U_W, 64, w * 16 + lo, kk * 32 + hi * 8);
        vfr[kk] = load_wfrag(V_W, 64, w * 16 + lo, kk * 32 + hi * 8);
    }
    #pragma unroll
    for (int kk = 0; kk < 4; kk++)
        w1fr[kk] = load_wfrag(aW1, 128, w * 16 + lo, kk * 32 + hi * 8);
    #pragma unroll
    for (int p = 0; p < 3; p++)
        #pragma unroll
        for (int kk = 0; kk < 2; kk++)
            w2fr[p][kk] = load_wfrag(aW2, 64, p * 64 + w * 16 + lo, kk * 32 + hi * 8);

    bf16x8 pws[2], pwr[2];
    #pragma unroll
    for (int kk = 0; kk < 2; kk++) {
        pws[kk] = load_wfrag(PW, 64, w * 16 + lo, kk * 32 + hi * 8);
        pwr[kk] = load_wfrag(PW, 64, 128 + w * 16 + lo, kk * 32 + hi * 8);
    }
    const float pbs = Pb[w * 16 + lo];
    const float pbr = Pb[128 + w * 16 + lo];

    const float ab1c  = ab1[w * 16 + lo];
    const float ab2c0 = ab2[w * 16 + lo];
    const float ab2c1 = ab2[64 + w * 16 + lo];
    const float ab2c2 = ab2[128 + w * 16 + lo];
    const int g = w * 16 + lo;

    for (int half = 0; half < 2; half++) {
        const int n0 = blockIdx.x * 64 + half * 32;
        if (half) __syncthreads();

        for (int u = tid; u < 96 * 8; u += 256) {
            int row = u >> 3, oct = u & 7;
            int d = row >> 5, nn = row & 31;
            int n = min(n0 + nn, N - 1);
            const float* src = v + ((size_t)n * 3 + d) * 64 + oct * 8;
            float4 a = *(const float4*)src;
            float4 b = *(const float4*)(src + 4);
            bf16x8 t;
            t[0] = f2bf(a.x); t[1] = f2bf(a.y); t[2] = f2bf(a.z); t[3] = f2bf(a.w);
            t[4] = f2bf(b.x); t[5] = f2bf(b.y); t[6] = f2bf(b.z); t[7] = f2bf(b.w);
            *(bf16x8*)&vlds[row * 72 + oct * 8] = t;
        }
        for (int u = tid; u < 32 * 8; u += 256) {
            int nn = u >> 3, oct = u & 7;
            int n = min(n0 + nn, N - 1);
            const float* src = s + (size_t)n * 64 + oct * 8;
            float4 a = *(const float4*)src;
            float4 b = *(const float4*)(src + 4);
            bf16x8 t;
            t[0] = f2bf(a.x); t[1] = f2bf(a.y); t[2] = f2bf(a.z); t[3] = f2bf(a.w);
            t[4] = f2bf(b.x); t[5] = f2bf(b.y); t[6] = f2bf(b.z); t[7] = f2bf(b.w);
            *(bf16x8*)&xlds[nn * 136 + oct * 8] = t;
        }
        __syncthreads();

        f32x4 cu[6], cv[6];
        #pragma unroll
        for (int mt = 0; mt < 6; mt++) { cu[mt] = (f32x4)0.0f; cv[mt] = (f32x4)0.0f; }
        #pragma unroll
        for (int kk = 0; kk < 2; kk++) {
            #pragma unroll
            for (int mt = 0; mt < 6; mt++) {
                bf16x8 af = *(const bf16x8*)&vlds[(mt * 16 + lo) * 72 + kk * 32 + hi * 8];
                cu[mt] = __builtin_amdgcn_mfma_f32_16x16x32_bf16(af, ufr[kk], cu[mt], 0, 0, 0);
                cv[mt] = __builtin_amdgcn_mfma_f32_16x16x32_bf16(af, vfr[kk], cv[mt], 0, 0, 0);
            }
        }

        f32x4 inn[2];
        #pragma unroll
        for (int nt = 0; nt < 2; nt++) {
            #pragma unroll
            for (int r = 0; r < 4; r++) {
                float vs = 0.f, ii = 0.f;
                #pragma unroll
                for (int d = 0; d < 3; d++) {
                    float a = cu[d * 2 + nt][r], b = cv[d * 2 + nt][r];
                    vs = fmaf(b, b, vs);
                    ii = fmaf(a, b, ii);
                }
                inn[nt][r] = ii;
                int nl = nt * 16 + hi * 4 + r;
                xlds[nl * 136 + 64 + w * 16 + lo] = f2bf(vs);
            }
        }
        __syncthreads();

        f32x4 c2[2];
        c2[0] = (f32x4)0.0f; c2[1] = (f32x4)0.0f;
        #pragma unroll
        for (int kk = 0; kk < 4; kk++) {
            #pragma unroll
            for (int mt = 0; mt < 2; mt++) {
                bf16x8 af = *(const bf16x8*)&xlds[(mt * 16 + lo) * 136 + kk * 32 + hi * 8];
                c2[mt] = __builtin_amdgcn_mfma_f32_16x16x32_bf16(af, w1fr[kk], c2[mt], 0, 0, 0);
            }
        }
        #pragma unroll
        for (int mt = 0; mt < 2; mt++)
            #pragma unroll
            for (int r = 0; r < 4; r++) {
                float hv = ssp_f(c2[mt][r] + ab1c);
                hlds[(mt * 16 + hi * 4 + r) * 72 + w * 16 + lo] = f2bf(hv);
            }
        __syncthreads();

        f32x4 c3[2][3];
        #pragma unroll
        for (int mt = 0; mt < 2; mt++)
            #pragma unroll
            for (int p = 0; p < 3; p++) c3[mt][p] = (f32x4)0.0f;
        #pragma unroll
        for (int kk = 0; kk < 2; kk++) {
            #pragma unroll
            for (int mt = 0; mt < 2; mt++) {
                bf16x8 af = *(const bf16x8*)&hlds[(mt * 16 + lo) * 72 + kk * 32 + hi * 8];
                #pragma unroll
                for (int p = 0; p < 3; p++)
                    c3[mt][p] = __builtin_amdgcn_mfma_f32_16x16x32_bf16(af, w2fr[p][kk], c3[mt][p], 0, 0, 0);
            }
        }

        float snew[2][4];
        #pragma unroll
        for (int mt = 0; mt < 2; mt++) {
            #pragma unroll
            for (int r = 0; r < 4; r++) {
                int n = n0 + mt * 16 + hi * 4 + r;
                if (n >= N) { snew[mt][r] = 0.f; continue; }
                float a_ss = c3[mt][0][r] + ab2c0;
                float a_sv = c3[mt][1][r] + ab2c1;
                float a_vv = c3[mt][2][r] + ab2c2;
                size_t si = (size_t)n * 64 + g;
                float sn = s[si] + a_ss + a_sv * inn[mt][r];
                s[si] = sn;
                snew[mt][r] = sn;
                float vn[3];
                #pragma unroll
                for (int d = 0; d < 3; d++) {
                    size_t vi = ((size_t)n * 3 + d) * 64 + g;
                    vn[d] = v[vi] + a_vv * cu[d * 2 + mt][r];
                    v[vi] = vn[d];
                }
                unsigned* pp = ndAV + ((size_t)n * 64 + g) * 3;
                pp[1] = (unsigned)(unsigned short)f2bf(vn[0])
                      | ((unsigned)(unsigned short)f2bf(vn[1]) << 16);
                pp[2] = (unsigned)(unsigned short)f2bf(vn[2]);
            }
        }

        // pack next-layer phi via MFMA on s_new
        __syncthreads();
        #pragma unroll
        for (int mt = 0; mt < 2; mt++)
            #pragma unroll
            for (int r = 0; r < 4; r++)
                hlds[(mt * 16 + hi * 4 + r) * 72 + g] = f2bf(snew[mt][r]);
        __syncthreads();

        f32x4 cs[2], cr[2];
        cs[0] = (f32x4)0.0f; cs[1] = (f32x4)0.0f;
        cr[0] = (f32x4)0.0f; cr[1] = (f32x4)0.0f;
        #pragma unroll
        for (int kk = 0; kk < 2; kk++) {
            #pragma unroll
            for (int mt = 0; mt < 2; mt++) {
                bf16x8 af = *(const bf16x8*)&hlds[(mt * 16 + lo) * 72 + kk * 32 + hi * 8];
                cs[mt] = __builtin_amdgcn_mfma_f32_16x16x32_bf16(af, pws[kk], cs[mt], 0, 0, 0);
                cr[mt] = __builtin_amdgcn_mfma_f32_16x16x32_bf16(af, pwr[kk], cr[mt], 0, 0, 0);
            }
        }
        #pragma unroll
        for (int mt = 0; mt < 2; mt++) {
            #pragma unroll
            for (int r = 0; r < 4; r++) {
                int n = n0 + mt * 16 + hi * 4 + r;
                if (n >= N) continue;
                ndAV[((size_t)n * 64 + g) * 3] =
                      (unsigned)(unsigned short)f2bf(cs[mt][r] + pbs)
                    | ((unsigned)(unsigned short)f2bf(cr[mt][r] + pbr) << 16);
            }
        }
    }
}

// ---------- layer-1 update FUSED with heads: per-node STORES (no atomics) ----------
__launch_bounds__(256)
__global__ void k_update_heads(const float* __restrict__ s, const float* __restrict__ v,
                               const float* __restrict__ U_W, const float* __restrict__ V_W,
                               const float* __restrict__ aW1, const float* __restrict__ ab1,
                               const float* __restrict__ aW2, const float* __restrict__ ab2,
                               const float* __restrict__ eW1, const float* __restrict__ eb1,
                               const float* __restrict__ eW2, const float* __restrict__ eb2,
                               const float* __restrict__ dip_w,
                               float* __restrict__ epsN, float* __restrict__ muN) {
    __shared__ short vlds[96 * 72];
    __shared__ short xlds[32 * 136];
    __shared__ short hlds[32 * 72];
    __shared__ float epsb[2][2][16];        // [node-half][col-half][node-in-16]
    __shared__ float dmub[4][2][16][3];     // [wave][mt][node-in-16][d]

    const int tid = threadIdx.x;
    const int l   = tid & 63;
    const int w   = tid >> 6;
    const int lo  = l & 15;
    const int hi  = l >> 4;

    bf16x8 ufr[2], vfr[2], w1fr[4], w2fr[3][2], e1fr[2];
    #pragma unroll
    for (int kk = 0; kk < 2; kk++) {
        ufr[kk] = load_wfrag(U_W, 64, w * 16 + lo, kk * 32 + hi * 8);
        vfr[kk] = load_wfrag(V_W, 64, w * 16 + lo, kk * 32 + hi * 8);
        e1fr[kk] = load_wfrag(eW1, 64, (w & 1) * 16 + lo, kk * 32 + hi * 8);
    }
    #pragma unroll
    for (int kk = 0; kk < 4; kk++)
        w1fr[kk] = load_wfrag(aW1, 128, w * 16 + lo, kk * 32 + hi * 8);
    #pragma unroll
    for (int p = 0; p < 3; p++)
        #pragma unroll
        for (int kk = 0; kk < 2; kk++)
            w2fr[p][kk] = load_wfrag(aW2, 64, p * 64 + w * 16 + lo, kk * 32 + hi * 8);

    const float ab1c  = ab1[w * 16 + lo];
    const float ab2c0 = ab2[w * 16 + lo];
    const float ab2c1 = ab2[64 + w * 16 + lo];
    const float ab2c2 = ab2[128 + w * 16 + lo];
    const float eb1v  = eb1[(w & 1) * 16 + lo];
    const float ew2v  = eW2[(w & 1) * 16 + lo];
    const float eb2c  = eb2[0];
    const int g = w * 16 + lo;
    const float dwv = dip_w[g];

    for (int half = 0; half < 2; half++) {
        const int n0 = blockIdx.x * 64 + half * 32;
        if (half) __syncthreads();

        for (int u = tid; u < 96 * 8; u += 256) {
            int row = u >> 3, oct = u & 7;
            int d = row >> 5, nn = row & 31;
            int n = min(n0 + nn, N - 1);
            const float* src = v + ((size_t)n * 3 + d) * 64 + oct * 8;
            float4 a = *(const float4*)src;
            float4 b = *(const float4*)(src + 4);
            bf16x8 t;
            t[0] = f2bf(a.x); t[1] = f2bf(a.y); t[2] = f2bf(a.z); t[3] = f2bf(a.w);
            t[4] = f2bf(b.x); t[5] = f2bf(b.y); t[6] = f2bf(b.z); t[7] = f2bf(b.w);
            *(bf16x8*)&vlds[row * 72 + oct * 8] = t;
        }
        for (int u = tid; u < 32 * 8; u += 256) {
            int nn = u >> 3, oct = u & 7;
            int n = min(n0 + nn, N - 1);
            const float* src = s + (size_t)n * 64 + oct * 8;
            float4 a = *(const float4*)src;
            float4 b = *(const float4*)(src + 4);
            bf16x8 t;
            t[0] = f2bf(a.x); t[1] = f2bf(a.y); t[2] = f2bf(a.z); t[3] = f2bf(a.w);
            t[4] = f2bf(b.x); t[5] = f2bf(b.y); t[6] = f2bf(b.z); t[7] = f2bf(b.w);
            *(bf16x8*)&xlds[nn * 136 + oct * 8] = t;
        }
        __syncthreads();

        f32x4 cu[6], cv[6];
        #pragma unroll
        for (int mt = 0; mt < 6; mt++) { cu[mt] = (f32x4)0.0f; cv[mt] = (f32x4)0.0f; }
        #pragma unroll
        for (int kk = 0; kk < 2; kk++) {
            #pragma unroll
            for (int mt = 0; mt < 6; mt++) {
                bf16x8 af = *(const bf16x8*)&vlds[(mt * 16 + lo) * 72 + kk * 32 + hi * 8];
                cu[mt] = __builtin_amdgcn_mfma_f32_16x16x32_bf16(af, ufr[kk], cu[mt], 0, 0, 0);
                cv[mt] = __builtin_amdgcn_mfma_f32_16x16x32_bf16(af, vfr[kk], cv[mt], 0, 0, 0);
            }
        }

        f32x4 inn[2];
        #pragma unroll
        for (int nt = 0; nt < 2; nt++) {
            #pragma unroll
            for (int r = 0; r < 4; r++) {
                float vs = 0.f, ii = 0.f;
                #pragma unroll
                for (int d = 0; d < 3; d++) {
                    float a = cu[d * 2 + nt][r], b = cv[d * 2 + nt][r];
                    vs = fmaf(b, b, vs);
                    ii = fmaf(a, b, ii);
                }
                inn[nt][r] = ii;
                int nl = nt * 16 + hi * 4 + r;
                xlds[nl * 136 + 64 + w * 16 + lo] = f2bf(vs);
            }
        }
        __syncthreads();

        f32x4 c2[2];
        c2[0] = (f32x4)0.0f; c2[1] = (f32x4)0.0f;
        #pragma unroll
        for (int kk = 0; kk < 4; kk++) {
            #pragma unroll
            for (int mt = 0; mt < 2; mt++) {
                bf16x8 af = *(const bf16x8*)&xlds[(mt * 16 + lo) * 136 + kk * 32 + hi * 8];
                c2[mt] = __builtin_amdgcn_mfma_f32_16x16x32_bf16(af, w1fr[kk], c2[mt], 0, 0, 0);
            }
        }
        #pragma unroll
        for (int mt = 0; mt < 2; mt++)
            #pragma unroll
            for (int r = 0; r < 4; r++) {
                float hv = ssp_f(c2[mt][r] + ab1c);
                hlds[(mt * 16 + hi * 4 + r) * 72 + w * 16 + lo] = f2bf(hv);
            }
        __syncthreads();

        f32x4 c3[2][3];
        #pragma unroll
        for (int mt = 0; mt < 2; mt++)
            #pragma unroll
            for (int p = 0; p < 3; p++) c3[mt][p] = (f32x4)0.0f;
        #pragma unroll
        for (int kk = 0; kk < 2; kk++) {
            #pragma unroll
            for (int mt = 0; mt < 2; mt++) {
                bf16x8 af = *(const bf16x8*)&hlds[(mt * 16 + lo) * 72 + kk * 32 + hi * 8];
                #pragma unroll
                for (int p = 0; p < 3; p++)
                    c3[mt][p] = __builtin_amdgcn_mfma_f32_16x16x32_bf16(af, w2fr[p][kk], c3[mt][p], 0, 0, 0);
            }
        }

        // epilogue: s_new/v_new kept in registers only (no global writeback)
        float snew[2][4];
        float vnk[2][4][3];
        #pragma unroll
        for (int mt = 0; mt < 2; mt++) {
            #pragma unroll
            for (int r = 0; r < 4; r++) {
                int n = n0 + mt * 16 + hi * 4 + r;
                if (n >= N) {
                    snew[mt][r] = 0.f;
                    vnk[mt][r][0] = vnk[mt][r][1] = vnk[mt][r][2] = 0.f;
                    continue;
                }
                float a_ss = c3[mt][0][r] + ab2c0;
                float a_sv = c3[mt][1][r] + ab2c1;
                float a_vv = c3[mt][2][r] + ab2c2;
                size_t si = (size_t)n * 64 + g;
                snew[mt][r] = s[si] + a_ss + a_sv * inn[mt][r];
                #pragma unroll
                for (int d = 0; d < 3; d++) {
                    size_t vi = ((size_t)n * 3 + d) * 64 + g;
                    vnk[mt][r][d] = v[vi] + a_vv * cu[d * 2 + mt][r];
                }
            }
        }

        // ---- heads: eps via MFMA on s_new ----
        __syncthreads();   // hlds free (GEMM3 done by all waves)
        #pragma unroll
        for (int mt = 0; mt < 2; mt++)
            #pragma unroll
            for (int r = 0; r < 4; r++)
                hlds[(mt * 16 + hi * 4 + r) * 72 + g] = f2bf(snew[mt][r]);
        __syncthreads();

        {
            const int a2 = w >> 1;
            f32x4 cx = (f32x4)0.0f;
            #pragma unroll
            for (int kk = 0; kk < 2; kk++) {
                bf16x8 af = *(const bf16x8*)&hlds[(a2 * 16 + lo) * 72 + kk * 32 + hi * 8];
                cx = __builtin_amdgcn_mfma_f32_16x16x32_bf16(af, e1fr[kk], cx, 0, 0, 0);
            }
            float part[4];
            #pragma unroll
            for (int r = 0; r < 4; r++)
                part[r] = ssp_f(cx[r] + eb1v) * ew2v;
            #pragma unroll
            for (int m2 = 1; m2 < 16; m2 <<= 1)
                #pragma unroll
                for (int r = 0; r < 4; r++)
                    part[r] += __shfl_xor(part[r], m2);
            if (lo == 0)
                #pragma unroll
                for (int r = 0; r < 4; r++)
                    epsb[a2][w & 1][hi * 4 + r] = part[r];
        }

        // ---- heads: dipole partials from v_new registers ----
        #pragma unroll
        for (int mt = 0; mt < 2; mt++)
            #pragma unroll
            for (int r = 0; r < 4; r++)
                #pragma unroll
                for (int d = 0; d < 3; d++) {
                    float val = dwv * vnk[mt][r][d];
                    #pragma unroll
                    for (int m2 = 1; m2 < 16; m2 <<= 1)
                        val += __shfl_xor(val, m2);
                    if (lo == 0) dmub[w][mt][hi * 4 + r][d] = val;
                }
        __syncthreads();

        // ---- combine + contention-free per-node stores ----
        if (tid < 32) {
            int nn = tid, a2 = nn >> 4, idx = nn & 15;
            int n = n0 + nn;
            if (n < N)
                epsN[n] = epsb[a2][0][idx] + epsb[a2][1][idx] + eb2c;
        } else if (tid >= 64 && tid < 160) {
            int t2 = tid - 64;
            int nn = t2 / 3, d = t2 % 3;
            int n = n0 + nn;
            if (n < N)
                muN[(size_t)d * N + n] =
                      dmub[0][nn >> 4][nn & 15][d] + dmub[1][nn >> 4][nn & 15][d]
                    + dmub[2][nn >> 4][nn & 15][d] + dmub[3][nn >> 4][nn & 15][d];
        }
    }
}

// ---------- heads reduction: LDS-accumulated, block-level atomics ----------
__global__ void k_heads_red(const float* __restrict__ epsN, const float* __restrict__ muN,
                            const int* __restrict__ bidx,
                            float* __restrict__ eacc, float* __restrict__ macc) {
    __shared__ float se[B];
    __shared__ float sm[3][B];
    if (threadIdx.x < B) se[threadIdx.x] = 0.0f;
    if (threadIdx.x < 3 * B) sm[threadIdx.x >> 6][threadIdx.x & 63] = 0.0f;
    __syncthreads();
    int n = blockIdx.x * blockDim.x + threadIdx.x;
    if (n < N) {
        int b = bidx[n];
        atomicAdd(&se[b], epsN[n]);
        #pragma unroll
        for (int d = 0; d < 3; d++)
            atomicAdd(&sm[d][b], muN[(size_t)d * N + n]);
    }
    __syncthreads();
    if (threadIdx.x < B) atomicAdd(&eacc[threadIdx.x], se[threadIdx.x]);
    if (threadIdx.x >= B && threadIdx.x < 4 * B) {
        int d = (threadIdx.x >> 6) - 1, b = threadIdx.x & 63;
        atomicAdd(&macc[d * B + b], sm[d][b]);
    }
}

__global__ void k_final(const float* __restrict__ eacc, const float* __restrict__ macc,
                        float* __restrict__ out) {
    int b = threadIdx.x;
    if (b < B) {
        out[b] = eacc[b];
        float mx = macc[b], my = macc[B + b], mz = macc[2 * B + b];
        out[B + b] = sqrtf(mx * mx + my * my + mz * mz);
    }
}

extern "C" void kernel_launch(void* const* d_in, const int* in_sizes, int n_in,
                              void* d_out, int out_size, void* d_ws, size_t ws_size,
                              hipStream_t stream) {
    const int*   z     = (const int*)d_in[0];
    const float* pos   = (const float*)d_in[1];
    const int*   ei    = (const int*)d_in[2];
    const int*   bidx  = (const int*)d_in[3];
    const float* emb   = (const float*)d_in[4];
    const float* phi_W = (const float*)d_in[5];
    const float* phi_b = (const float*)d_in[6];
    const float* fW1   = (const float*)d_in[7];
    const float* fb1   = (const float*)d_in[8];
    const float* fW2   = (const float*)d_in[9];
    const float* fb2   = (const float*)d_in[10];
    const float* U_W   = (const float*)d_in[11];
    const float* V_W   = (const float*)d_in[12];
    const float* aW1   = (const float*)d_in[13];
    const float* ab1   = (const float*)d_in[14];
    const float* aW2   = (const float*)d_in[15];
    const float* ab2   = (const float*)d_in[16];
    const float* eW1   = (const float*)d_in[17];
    const float* eb1   = (const float*)d_in[18];
    const float* eW2   = (const float*)d_in[19];
    const float* eb2   = (const float*)d_in[20];
    const float* dip_w = (const float*)d_in[21];
    float* out = (float*)d_out;

    // ---- workspace carve-up ----
    float* ws = (float*)d_ws;
    float* s    = ws;                                  // N*64 f32
    float* v    = s + (size_t)N * F;                   // N*192 f32
    unsigned* ndA0 = (unsigned*)(v + (size_t)N * F * 3);  // N*64 uint (L0 record)
    unsigned* ndAV = ndA0 + (size_t)N * 64;            // N*64*3 uint (L1 fused record)
    unsigned short* Tp = (unsigned short*)(ndAV + (size_t)N * 64 * 3); // NL*TENTA*256 u16
    float* eacc = (float*)(Tp + (size_t)NL * TENTA * 256); // B
    float* macc = eacc + B;                            // 3B
    float* epsN = macc + 3 * B;                        // N
    float* muN  = epsN + N;                            // 3N
    int*   cnt  = (int*)(muN + 3 * (size_t)N);         // N
    int*   off  = cnt  + N;                            // N+1
    int*   cur  = off  + N + 1;                        // N
    int*   bsum = cur  + N;                            // 256
    int*   bpre = bsum + 256;                          // 256
    uint4* edata = (uint4*)(((uintptr_t)(bpre + 256) + 15) & ~(uintptr_t)15); // (E+N)*16B

    hipMemsetAsync(cnt,  0, sizeof(int) * N, stream);
    hipMemsetAsync(eacc, 0, sizeof(float) * 4 * B, stream);
    hipMemsetAsync(out + 2 * B, 0, sizeof(float) * (size_t)N, stream); // charges

    k_hist<<<(E + 255) / 256, 256, 0, stream>>>(ei, cnt);
    k_scan_a<<<NBLK_SCAN, 256, 0, stream>>>(cnt, bsum);
    k_scan_b<<<1, 256, 0, stream>>>(bsum, bpre, off + N);
    k_scan_c<<<NBLK_SCAN, 256, 0, stream>>>(cnt, bpre, off, cur, edata);
    k_scatter<<<(E + 255) / 256, 256, 0, stream>>>(ei, cur, pos, edata);
    k_table<<<(NL * (NB + 1) + 3) / 4, 256, 0, stream>>>(fW1, fb1, fW2, fb2, Tp);

    const int gblocks = (N + 1) / 2;
    const int ublocks = (N + 63) / 64;
    // layer 0
    k_pack0<<<512, 256, 0, stream>>>(s, z, emb, phi_W, phi_b, ndA0);
    k_gather<false><<<gblocks, 128, 0, stream>>>(edata, off, Tp, ndA0, ndAV, s, v);
    k_update_mfma<<<ublocks, 256, 0, stream>>>(s, v,
        U_W, V_W, aW1, ab1, aW2, ab2,
        phi_W + (size_t)192 * 64, phi_b + 192, ndAV);
    // layer 1 (update fused with heads; per-node stores, no s/v writeback)
    k_gather<true><<<gblocks, 128, 0, stream>>>(edata, off,
        Tp + (size_t)TENTA * 256, ndA0, ndAV, s, v);
    k_update_heads<<<ublocks, 256, 0, stream>>>(s, v,
        U_W + 4096, V_W + 4096, aW1 + 8192, ab1 + F, aW2 + 12288, ab2 + 192,
        eW1, eb1, eW2, eb2, dip_w, epsN, muN);
    k_heads_red<<<(N + 255) / 256, 256, 0, stream>>>(epsN, muN, bidx, eacc, macc);

    k_final<<<1, 64, 0, stream>>>(eacc, macc, out);
}

// Round 16
// 473.892 us; speedup vs baseline: 1.6875x; 1.0077x over previous
//
#include <hip/hip_runtime.h>
#include <math.h>

static constexpr int N  = 50000;
static constexpr int E  = 800000;
static constexpr int F  = 64;
static constexpr int R  = 20;
static constexpr int NL = 2;
static constexpr int B  = 64;
static constexpr float RC   = 5.0f;
static constexpr float LN2F = 0.6931471805599453f;
static constexpr float WIDTH  = RC / (R - 1);
static constexpr float INV2W2 = 1.0f / (2.0f * WIDTH * WIDTH);
static constexpr float PI_F = 3.14159265358979323846f;

// filt(r) nearest-neighbor lookup table: NB intervals on [0,RC]
static constexpr int   NB     = 4096;
static constexpr float DR     = RC / NB;
static constexpr float INV_DR = NB / RC;
static constexpr int   IZERO  = NB + 1;   // all-zero entry (null/pad edges)
static constexpr int   TENTA  = NB + 2;   // entries: 0..NB real, NB+1 zero
// entry = 64 lanes x 4 ushorts {Ws, Wv, Wr, 0} = 512 B

static constexpr int NBLK_SCAN = (N + 255) / 256;  // 196

typedef __attribute__((ext_vector_type(8))) short bf16x8;
typedef __attribute__((ext_vector_type(4))) float f32x4;
typedef __attribute__((ext_vector_type(3))) unsigned uint32x3;

__device__ __forceinline__ float ssp_f(float x) {
    return fmaxf(x, 0.0f) + log1pf(__expf(-fabsf(x))) - LN2F;
}

__device__ __forceinline__ short f2bf(float x) {
    unsigned u = __builtin_bit_cast(unsigned, x);
    unsigned r = (u + 0x7fffu + ((u >> 16) & 1u)) >> 16;
    return (short)r;
}
__device__ __forceinline__ float bf_lo(unsigned u) {
    return __builtin_bit_cast(float, u << 16);
}
__device__ __forceinline__ float bf_hi(unsigned u) {
    return __builtin_bit_cast(float, u & 0xffff0000u);
}

// ---------- counting sort of edges by src, runs padded to multiple of 2 ----------
__global__ void k_hist(const int* __restrict__ ei, int* __restrict__ cnt) {
    int e = blockIdx.x * blockDim.x + threadIdx.x;
    if (e < E) atomicAdd(&cnt[ei[e]], 1);
}

__global__ void k_scan_a(const int* __restrict__ cnt, int* __restrict__ bsum) {
    __shared__ int part[256];
    const int t = threadIdx.x;
    const int idx = blockIdx.x * 256 + t;
    int v = (idx < N) ? ((cnt[idx] + 1) & ~1) : 0;   // padded count
    part[t] = v;
    __syncthreads();
    for (int d = 1; d < 256; d <<= 1) {
        int x = (t >= d) ? part[t - d] : 0;
        __syncthreads();
        part[t] += x;
        __syncthreads();
    }
    if (t == 255) bsum[blockIdx.x] = part[255];
}

__global__ void k_scan_b(const int* __restrict__ bsum, int* __restrict__ bpre,
                         int* __restrict__ offN) {
    __shared__ int part[256];
    const int t = threadIdx.x;
    int v = (t < NBLK_SCAN) ? bsum[t] : 0;
    part[t] = v;
    __syncthreads();
    for (int d = 1; d < 256; d <<= 1) {
        int x = (t >= d) ? part[t - d] : 0;
        __syncthreads();
        part[t] += x;
        __syncthreads();
    }
    if (t < NBLK_SCAN) bpre[t] = part[t] - v;   // exclusive
    if (t == NBLK_SCAN - 1) *offN = part[t];    // off[N] = padded total
}

// computes padded offsets; also writes the null pad descriptor for odd-degree nodes
__global__ void k_scan_c(const int* __restrict__ cnt, const int* __restrict__ bpre,
                         int* __restrict__ off, int* __restrict__ cur,
                         uint4* __restrict__ edata) {
    __shared__ int part[256];
    const int t = threadIdx.x;
    const int idx = blockIdx.x * 256 + t;
    int vraw = (idx < N) ? cnt[idx] : 0;
    int v = (vraw + 1) & ~1;
    part[t] = v;
    __syncthreads();
    for (int d = 1; d < 256; d <<= 1) {
        int x = (t >= d) ? part[t - d] : 0;
        __syncthreads();
        part[t] += x;
        __syncthreads();
    }
    if (idx < N) {
        int e = bpre[blockIdx.x] + part[t] - v;
        off[idx] = e;
        cur[idx] = e;
        if (vraw & 1) {
            uint4 nil;
            nil.x = (unsigned)idx * 256u;          // record byte offset (self)
            nil.y = (unsigned)IZERO * 512u;        // zero table entry byte offset
            nil.z = 0u; nil.w = 0u;
            edata[e + vraw] = nil;
        }
    }
}

// scatter one 16B record per CSR slot: {dst*256, i*512, qx|qy, qz}
__global__ void k_scatter(const int* __restrict__ ei, int* __restrict__ cur,
                          const float* __restrict__ pos, uint4* __restrict__ edata) {
    int e = blockIdx.x * blockDim.x + threadIdx.x;
    if (e >= E) return;
    int src = ei[e], dst = ei[E + e];
    int p = atomicAdd(&cur[src], 1);
    float qx = pos[dst * 3 + 0] - pos[src * 3 + 0];
    float qy = pos[dst * 3 + 1] - pos[src * 3 + 1];
    float qz = pos[dst * 3 + 2] - pos[src * 3 + 2];
    float rn = sqrtf(qx * qx + qy * qy + qz * qz);
    float invn = 1.0f / fmaxf(rn, 1e-8f);
    int i = (int)(rn * INV_DR + 0.5f);     // nearest-neighbor bin
    if (i > NB) i = NB;                    // constant region (fc = 0)
    uint4 rec;
    rec.x = (unsigned)dst * 256u;
    rec.y = (unsigned)i * 512u;
    rec.z = (unsigned)(unsigned short)f2bf(qx * invn)
          | ((unsigned)(unsigned short)f2bf(qy * invn) << 16);
    rec.w = (unsigned)(unsigned short)f2bf(qz * invn);
    edata[p] = rec;
}

// ---------- filt(r) NN table: entry i, lane: {Ws, Wv, Wr, 0} (8B/lane) ----------
__global__ void k_table(const float* __restrict__ fW1, const float* __restrict__ fb1,
                        const float* __restrict__ fW2, const float* __restrict__ fb2,
                        unsigned short* __restrict__ Tp) {
    __shared__ float sh[4][F];
    const int wid  = threadIdx.x >> 6;
    const int lane = threadIdx.x & 63;
    const int gid  = blockIdx.x * 4 + wid;          // flattened (l,row), row in [0,NB]
    if (gid >= NL * (NB + 1)) return;
    const int l   = gid / (NB + 1);
    const int row = gid % (NB + 1);
    const float r = (float)row * DR;
    const float fc = (r < RC) ? 0.5f * (__cosf(PI_F * r * (1.0f / RC)) + 1.0f) : 0.0f;

    float acc = fb1[l * F + lane];
    const float* w1 = fW1 + (size_t)l * F * R + (size_t)lane * R;
    #pragma unroll
    for (int rr = 0; rr < R; rr++) {
        float dmu = r - rr * WIDTH;
        float er = __expf(-dmu * dmu * INV2W2) * fc;
        acc = fmaf(er, w1[rr], acc);
    }
    sh[wid][lane] = ssp_f(acc);
    __syncthreads();
    unsigned short* TpL = Tp + (size_t)l * TENTA * 256;
    #pragma unroll
    for (int p = 0; p < 3; p++) {
        int c = p * 64 + lane;
        float a = fb2[l * 192 + c];
        const float* w2 = fW2 + ((size_t)l * 192 + c) * 64;
        #pragma unroll 8
        for (int k = 0; k < F; k++) a = fmaf(sh[wid][k], w2[k], a);
        TpL[(size_t)row * 256 + lane * 4 + p] = (unsigned short)f2bf(a);
    }
    TpL[(size_t)row * 256 + lane * 4 + 3] = 0;
    if (row == 0) {   // zero entry for pad edges
        #pragma unroll
        for (int j = 0; j < 4; j++)
            TpL[(size_t)IZERO * 256 + lane * 4 + j] = 0;
    }
}

// ---------- layer-0 pack: init s from emb[z], write dense ndA0 = phi_s|phi_r ----------
__launch_bounds__(256)
__global__ void k_pack0(float* __restrict__ s, const int* __restrict__ z,
                        const float* __restrict__ emb,
                        const float* __restrict__ PW, const float* __restrict__ Pb,
                        unsigned* __restrict__ ndA0) {
    __shared__ float sbuf[4][F];
    const int lane = threadIdx.x & 63;
    const int wid  = threadIdx.x >> 6;
    const int gwave = blockIdx.x * 4 + wid;
    const int nwaves = gridDim.x * 4;

    float wsr[F], wrr[F];
    {
        const float* rs = PW + (size_t)lane * 64;
        const float* rr = PW + (size_t)(128 + lane) * 64;
        #pragma unroll
        for (int k = 0; k < F; k += 4) {
            float4 a = *(const float4*)(rs + k);
            wsr[k] = a.x; wsr[k+1] = a.y; wsr[k+2] = a.z; wsr[k+3] = a.w;
            float4 b = *(const float4*)(rr + k);
            wrr[k] = b.x; wrr[k+1] = b.y; wrr[k+2] = b.z; wrr[k+3] = b.w;
        }
    }
    const float bs = Pb[lane], br = Pb[128 + lane];

    for (int n = gwave; n < N; n += nwaves) {
        float sv = emb[(size_t)z[n] * F + lane];
        s[(size_t)n * F + lane] = sv;
        sbuf[wid][lane] = sv;
        float as = bs, ar = br;
        #pragma unroll
        for (int k = 0; k < F; k += 4) {
            float4 s4 = *(const float4*)&sbuf[wid][k];
            as = fmaf(s4.x, wsr[k],   as); as = fmaf(s4.y, wsr[k+1], as);
            as = fmaf(s4.z, wsr[k+2], as); as = fmaf(s4.w, wsr[k+3], as);
            ar = fmaf(s4.x, wrr[k],   ar); ar = fmaf(s4.y, wrr[k+1], ar);
            ar = fmaf(s4.z, wrr[k+2], ar); ar = fmaf(s4.w, wrr[k+3], ar);
        }
        ndA0[(size_t)n * 64 + lane] = (unsigned)(unsigned short)f2bf(as)
                                    | ((unsigned)(unsigned short)f2bf(ar) << 16);
    }
}

// ---------- gather/message kernel: WAVE per node, 2 nodes/block; v stored bf16 ----------
template<bool ACCUMV>
__device__ __forceinline__ void consume_edge(const uint4 ed, const uint2 t,
                                             const uint32x3 r,
                                             float& ms, float& mv0, float& mv1, float& mv2) {
    const float Ws = bf_lo(t.x);
    const float Wr = bf_lo(t.y);
    ms = fmaf(Ws, bf_lo(r.x), ms);
    const float c = Wr * bf_hi(r.x);
    const float rhx = bf_lo(ed.z), rhy = bf_hi(ed.z), rhz = bf_lo(ed.w);
    if (ACCUMV) {
        const float Wv = bf_hi(t.x);
        mv0 = fmaf(Wv, bf_lo(r.y), fmaf(c, rhx, mv0));
        mv1 = fmaf(Wv, bf_hi(r.y), fmaf(c, rhy, mv1));
        mv2 = fmaf(Wv, bf_lo(r.z), fmaf(c, rhz, mv2));
    } else {
        mv0 = fmaf(c, rhx, mv0);
        mv1 = fmaf(c, rhy, mv1);
        mv2 = fmaf(c, rhz, mv2);
    }
}

template<bool ACCUMV>
__device__ __forceinline__ uint2 load_tbl(const char* __restrict__ tb, unsigned yoff) {
    return *(const uint2*)(tb + yoff);
}
template<bool ACCUMV>
__device__ __forceinline__ uint32x3 load_rec(const char* __restrict__ rb0,
                                             const char* __restrict__ rbV, unsigned xoff) {
    uint32x3 r;
    if (ACCUMV) {
        r = *(const uint32x3*)(rbV + (size_t)xoff * 3);
    } else {
        r.x = *(const unsigned*)(rb0 + xoff); r.y = 0; r.z = 0;
    }
    return r;
}

template<bool ACCUMV>
__launch_bounds__(128, 8)
__global__ void k_gather(const uint4* __restrict__ edata, const int* __restrict__ off,
                         const unsigned short* __restrict__ TpL,
                         const unsigned* __restrict__ ndA0,
                         const unsigned* __restrict__ ndAV,
                         float* __restrict__ s, unsigned short* __restrict__ vb) {
    const int lane = threadIdx.x & 63;
    const int wv   = threadIdx.x >> 6;
    const int n = blockIdx.x * 2 + wv;
    if (n >= N) return;
    const int base = off[n], end = off[n + 1];   // even length

    const char* tb  = (const char*)TpL  + lane * 8;
    const char* rb0 = (const char*)ndA0 + lane * 4;
    const char* rbV = (const char*)ndAV + lane * 12;

    float ms = 0.f, mv0 = 0.f, mv1 = 0.f, mv2 = 0.f;

    if (base < end) {
        uint4 ed0 = edata[base];
        uint4 ed1 = edata[base + 1];
        uint2    t0 = load_tbl<ACCUMV>(tb, ed0.y);
        uint32x3 r0 = load_rec<ACCUMV>(rb0, rbV, ed0.x);

        for (int k = base; k < end - 2; ++k) {
            uint4 ed2 = edata[k + 2];
            uint2    t1 = load_tbl<ACCUMV>(tb, ed1.y);
            uint32x3 r1 = load_rec<ACCUMV>(rb0, rbV, ed1.x);
            consume_edge<ACCUMV>(ed0, t0, r0, ms, mv0, mv1, mv2);
            ed0 = ed1; t0 = t1; r0 = r1;
            ed1 = ed2;
        }
        // epilogue: last two edges
        uint2    t1 = load_tbl<ACCUMV>(tb, ed1.y);
        uint32x3 r1 = load_rec<ACCUMV>(rb0, rbV, ed1.x);
        consume_edge<ACCUMV>(ed0, t0, r0, ms, mv0, mv1, mv2);
        consume_edge<ACCUMV>(ed1, t1, r1, ms, mv0, mv1, mv2);
    }

    s[(size_t)n * F + lane] += ms;
    unsigned short* vo = vb + (size_t)n * 192 + lane;
    if (ACCUMV) {
        vo[0]   = (unsigned short)f2bf(bf_lo((unsigned)vo[0])   + mv0);
        vo[64]  = (unsigned short)f2bf(bf_lo((unsigned)vo[64])  + mv1);
        vo[128] = (unsigned short)f2bf(bf_lo((unsigned)vo[128]) + mv2);
    } else {
        vo[0]   = (unsigned short)f2bf(mv0);
        vo[64]  = (unsigned short)f2bf(mv1);
        vo[128] = (unsigned short)f2bf(mv2);
    }
}

// ---------- MFMA node-update helpers ----------
__device__ __forceinline__ bf16x8 load_wfrag(const float* __restrict__ Wp, int ldk,
                                             int nrow, int k0) {
    const float* p = Wp + (size_t)nrow * ldk + k0;
    float4 a = *(const float4*)p;
    float4 b = *(const float4*)(p + 4);
    bf16x8 r;
    r[0] = f2bf(a.x); r[1] = f2bf(a.y); r[2] = f2bf(a.z); r[3] = f2bf(a.w);
    r[4] = f2bf(b.x); r[5] = f2bf(b.y); r[6] = f2bf(b.z); r[7] = f2bf(b.w);
    return r;
}

// ---------- layer-0 update: 64 nodes/block, writes s,vb and next-layer ndAV ----------
__launch_bounds__(256)
__global__ void k_update_mfma(float* __restrict__ s, unsigned short* __restrict__ vb,
                              const float* __restrict__ U_W, const float* __restrict__ V_W,
                              const float* __restrict__ aW1, const float* __restrict__ ab1,
                              const float* __restrict__ aW2, const float* __restrict__ ab2,
                              const float* __restrict__ PW, const float* __restrict__ Pb,
                              unsigned* __restrict__ ndAV) {
    __shared__ short vlds[96 * 72];
    __shared__ short xlds[32 * 136];
    __shared__ short hlds[32 * 72];

    const int tid = threadIdx.x;
    const int l   = tid & 63;
    const int w   = tid >> 6;
    const int lo  = l & 15;
    const int hi  = l >> 4;

    bf16x8 ufr[2], vfr[2], w1fr[4], w2fr[3][2];
    #pragma unroll
    for (int kk = 0; kk < 2; kk++) {
        ufr[kk] = load_wfrag(U_W, 64, w * 16 + lo, kk * 32 + hi * 8);
        vfr[kk] = load_wfrag(V_W, 64, w * 16 + lo, kk * 32 + hi * 8);
    }
    #pragma unroll
    for (int kk = 0; kk < 4; kk++)
        w1fr[kk] = load_wfrag(aW1, 128, w * 16 + lo, kk * 32 + hi * 8);
    #pragma unroll
    for (int p = 0; p < 3; p++)
        #pragma unroll
        for (int kk = 0; kk < 2; kk++)
            w2fr[p][kk] = load_wfrag(aW2, 64, p * 64 + w * 16 + lo, kk * 32 + hi * 8);

    bf16x8 pws[2], pwr[2];
    #pragma unroll
    for (int kk = 0; kk < 2; kk++) {
        pws[kk] = load_wfrag(PW, 64, w * 16 + lo, kk * 32 + hi * 8);
        pwr[kk] = load_wfrag(PW, 64, 128 + w * 16 + lo, kk * 32 + hi * 8);
    }
    const float pbs = Pb[w * 16 + lo];
    const float pbr = Pb[128 + w * 16 + lo];

    const float ab1c  = ab1[w * 16 + lo];
    const float ab2c0 = ab2[w * 16 + lo];
    const float ab2c1 = ab2[64 + w * 16 + lo];
    const float ab2c2 = ab2[128 + w * 16 + lo];
    const int g = w * 16 + lo;

    for (int half = 0; half < 2; half++) {
        const int n0 = blockIdx.x * 64 + half * 32;
        if (half) __syncthreads();

        // --- stage v (bf16 direct copy) into vlds, s (convert) into xlds[:,0:64] ---
        for (int u = tid; u < 96 * 8; u += 256) {
            int row = u >> 3, oct = u & 7;
            int d = row >> 5, nn = row & 31;
            int n = min(n0 + nn, N - 1);
            bf16x8 t = *(const bf16x8*)(vb + ((size_t)n * 3 + d) * 64 + oct * 8);
            *(bf16x8*)&vlds[row * 72 + oct * 8] = t;
        }
        for (int u = tid; u < 32 * 8; u += 256) {
            int nn = u >> 3, oct = u & 7;
            int n = min(n0 + nn, N - 1);
            const float* src = s + (size_t)n * 64 + oct * 8;
            float4 a = *(const float4*)src;
            float4 b = *(const float4*)(src + 4);
            bf16x8 t;
            t[0] = f2bf(a.x); t[1] = f2bf(a.y); t[2] = f2bf(a.z); t[3] = f2bf(a.w);
            t[4] = f2bf(b.x); t[5] = f2bf(b.y); t[6] = f2bf(b.z); t[7] = f2bf(b.w);
            *(bf16x8*)&xlds[nn * 136 + oct * 8] = t;
        }
        __syncthreads();

        f32x4 cu[6], cv[6];
        #pragma unroll
        for (int mt = 0; mt < 6; mt++) { cu[mt] = (f32x4)0.0f; cv[mt] = (f32x4)0.0f; }
        #pragma unroll
        for (int kk = 0; kk < 2; kk++) {
            #pragma unroll
            for (int mt = 0; mt < 6; mt++) {
                bf16x8 af = *(const bf16x8*)&vlds[(mt * 16 + lo) * 72 + kk * 32 + hi * 8];
                cu[mt] = __builtin_amdgcn_mfma_f32_16x16x32_bf16(af, ufr[kk], cu[mt], 0, 0, 0);
                cv[mt] = __builtin_amdgcn_mfma_f32_16x16x32_bf16(af, vfr[kk], cv[mt], 0, 0, 0);
            }
        }

        f32x4 inn[2];
        #pragma unroll
        for (int nt = 0; nt < 2; nt++) {
            #pragma unroll
            for (int r = 0; r < 4; r++) {
                float vs = 0.f, ii = 0.f;
                #pragma unroll
                for (int d = 0; d < 3; d++) {
                    float a = cu[d * 2 + nt][r], b = cv[d * 2 + nt][r];
                    vs = fmaf(b, b, vs);
                    ii = fmaf(a, b, ii);
                }
                inn[nt][r] = ii;
                int nl = nt * 16 + hi * 4 + r;
                xlds[nl * 136 + 64 + w * 16 + lo] = f2bf(vs);
            }
        }
        __syncthreads();

        f32x4 c2[2];
        c2[0] = (f32x4)0.0f; c2[1] = (f32x4)0.0f;
        #pragma unroll
        for (int kk = 0; kk < 4; kk++) {
            #pragma unroll
            for (int mt = 0; mt < 2; mt++) {
                bf16x8 af = *(const bf16x8*)&xlds[(mt * 16 + lo) * 136 + kk * 32 + hi * 8];
                c2[mt] = __builtin_amdgcn_mfma_f32_16x16x32_bf16(af, w1fr[kk], c2[mt], 0, 0, 0);
            }
        }
        #pragma unroll
        for (int mt = 0; mt < 2; mt++)
            #pragma unroll
            for (int r = 0; r < 4; r++) {
                float hv = ssp_f(c2[mt][r] + ab1c);
                hlds[(mt * 16 + hi * 4 + r) * 72 + w * 16 + lo] = f2bf(hv);
            }
        __syncthreads();

        f32x4 c3[2][3];
        #pragma unroll
        for (int mt = 0; mt < 2; mt++)
            #pragma unroll
            for (int p = 0; p < 3; p++) c3[mt][p] = (f32x4)0.0f;
        #pragma unroll
        for (int kk = 0; kk < 2; kk++) {
            #pragma unroll
            for (int mt = 0; mt < 2; mt++) {
                bf16x8 af = *(const bf16x8*)&hlds[(mt * 16 + lo) * 72 + kk * 32 + hi * 8];
                #pragma unroll
                for (int p = 0; p < 3; p++)
                    c3[mt][p] = __builtin_amdgcn_mfma_f32_16x16x32_bf16(af, w2fr[p][kk], c3[mt][p], 0, 0, 0);
            }
        }

        float snew[2][4];
        #pragma unroll
        for (int mt = 0; mt < 2; mt++) {
            #pragma unroll
            for (int r = 0; r < 4; r++) {
                int n = n0 + mt * 16 + hi * 4 + r;
                if (n >= N) { snew[mt][r] = 0.f; continue; }
                float a_ss = c3[mt][0][r] + ab2c0;
                float a_sv = c3[mt][1][r] + ab2c1;
                float a_vv = c3[mt][2][r] + ab2c2;
                size_t si = (size_t)n * 64 + g;
                float sn = s[si] + a_ss + a_sv * inn[mt][r];
                s[si] = sn;
                snew[mt][r] = sn;
                float vn[3];
                #pragma unroll
                for (int d = 0; d < 3; d++) {
                    size_t vi = ((size_t)n * 3 + d) * 64 + g;
                    float vold = bf_lo((unsigned)vb[vi]);
                    vn[d] = vold + a_vv * cu[d * 2 + mt][r];
                    vb[vi] = (unsigned short)f2bf(vn[d]);
                }
                unsigned* pp = ndAV + ((size_t)n * 64 + g) * 3;
                pp[1] = (unsigned)(unsigned short)f2bf(vn[0])
                      | ((unsigned)(unsigned short)f2bf(vn[1]) << 16);
                pp[2] = (unsigned)(unsigned short)f2bf(vn[2]);
            }
        }

        // pack next-layer phi via MFMA on s_new
        __syncthreads();
        #pragma unroll
        for (int mt = 0; mt < 2; mt++)
            #pragma unroll
            for (int r = 0; r < 4; r++)
                hlds[(mt * 16 + hi * 4 + r) * 72 + g] = f2bf(snew[mt][r]);
        __syncthreads();

        f32x4 cs[2], cr[2];
        cs[0] = (f32x4)0.0f; cs[1] = (f32x4)0.0f;
        cr[0] = (f32x4)0.0f; cr[1] = (f32x4)0.0f;
        #pragma unroll
        for (int kk = 0; kk < 2; kk++) {
            #pragma unroll
            for (int mt = 0; mt < 2; mt++) {
                bf16x8 af = *(const bf16x8*)&hlds[(mt * 16 + lo) * 72 + kk * 32 + hi * 8];
                cs[mt] = __builtin_amdgcn_mfma_f32_16x16x32_bf16(af, pws[kk], cs[mt], 0, 0, 0);
                cr[mt] = __builtin_amdgcn_mfma_f32_16x16x32_bf16(af, pwr[kk], cr[mt], 0, 0, 0);
            }
        }
        #pragma unroll
        for (int mt = 0; mt < 2; mt++) {
            #pragma unroll
            for (int r = 0; r < 4; r++) {
                int n = n0 + mt * 16 + hi * 4 + r;
                if (n >= N) continue;
                ndAV[((size_t)n * 64 + g) * 3] =
                      (unsigned)(unsigned short)f2bf(cs[mt][r] + pbs)
                    | ((unsigned)(unsigned short)f2bf(cr[mt][r] + pbr) << 16);
            }
        }
    }
}

// ---------- layer-1 update FUSED with heads: per-node STORES (no atomics) ----------
__launch_bounds__(256)
__global__ void k_update_heads(const float* __restrict__ s,
                               const unsigned short* __restrict__ vb,
                               const float* __restrict__ U_W, const float* __restrict__ V_W,
                               const float* __restrict__ aW1, const float* __restrict__ ab1,
                               const float* __restrict__ aW2, const float* __restrict__ ab2,
                               const float* __restrict__ eW1, const float* __restrict__ eb1,
                               const float* __restrict__ eW2, const float* __restrict__ eb2,
                               const float* __restrict__ dip_w,
                               float* __restrict__ epsN, float* __restrict__ muN) {
    __shared__ short vlds[96 * 72];
    __shared__ short xlds[32 * 136];
    __shared__ short hlds[32 * 72];
    __shared__ float epsb[2][2][16];        // [node-half][col-half][node-in-16]
    __shared__ float dmub[4][2][16][3];     // [wave][mt][node-in-16][d]

    const int tid = threadIdx.x;
    const int l   = tid & 63;
    const int w   = tid >> 6;
    const int lo  = l & 15;
    const int hi  = l >> 4;

    bf16x8 ufr[2], vfr[2], w1fr[4], w2fr[3][2], e1fr[2];
    #pragma unroll
    for (int kk = 0; kk < 2; kk++) {
        ufr[kk] = load_wfrag(U_W, 64, w * 16 + lo, kk * 32 + hi * 8);
        vfr[kk] = load_wfrag(V_W, 64, w * 16 + lo, kk * 32 + hi * 8);
        e1fr[kk] = load_wfrag(eW1, 64, (w & 1) * 16 + lo, kk * 32 + hi * 8);
    }
    #pragma unroll
    for (int kk = 0; kk < 4; kk++)
        w1fr[kk] = load_wfrag(aW1, 128, w * 16 + lo, kk * 32 + hi * 8);
    #pragma unroll
    for (int p = 0; p < 3; p++)
        #pragma unroll
        for (int kk = 0; kk < 2; kk++)
            w2fr[p][kk] = load_wfrag(aW2, 64, p * 64 + w * 16 + lo, kk * 32 + hi * 8);

    const float ab1c  = ab1[w * 16 + lo];
    const float ab2c0 = ab2[w * 16 + lo];
    const float ab2c1 = ab2[64 + w * 16 + lo];
    const float ab2c2 = ab2[128 + w * 16 + lo];
    const float eb1v  = eb1[(w & 1) * 16 + lo];
    const float ew2v  = eW2[(w & 1) * 16 + lo];
    const float eb2c  = eb2[0];
    const int g = w * 16 + lo;
    const float dwv = dip_w[g];

    for (int half = 0; half < 2; half++) {
        const int n0 = blockIdx.x * 64 + half * 32;
        if (half) __syncthreads();

        for (int u = tid; u < 96 * 8; u += 256) {
            int row = u >> 3, oct = u & 7;
            int d = row >> 5, nn = row & 31;
            int n = min(n0 + nn, N - 1);
            bf16x8 t = *(const bf16x8*)(vb + ((size_t)n * 3 + d) * 64 + oct * 8);
            *(bf16x8*)&vlds[row * 72 + oct * 8] = t;
        }
        for (int u = tid; u < 32 * 8; u += 256) {
            int nn = u >> 3, oct = u & 7;
            int n = min(n0 + nn, N - 1);
            const float* src = s + (size_t)n * 64 + oct * 8;
            float4 a = *(const float4*)src;
            float4 b = *(const float4*)(src + 4);
            bf16x8 t;
            t[0] = f2bf(a.x); t[1] = f2bf(a.y); t[2] = f2bf(a.z); t[3] = f2bf(a.w);
            t[4] = f2bf(b.x); t[5] = f2bf(b.y); t[6] = f2bf(b.z); t[7] = f2bf(b.w);
            *(bf16x8*)&xlds[nn * 136 + oct * 8] = t;
        }
        __syncthreads();

        f32x4 cu[6], cv[6];
        #pragma unroll
        for (int mt = 0; mt < 6; mt++) { cu[mt] = (f32x4)0.0f; cv[mt] = (f32x4)0.0f; }
        #pragma unroll
        for (int kk = 0; kk < 2; kk++) {
            #pragma unroll
            for (int mt = 0; mt < 6; mt++) {
                bf16x8 af = *(const bf16x8*)&vlds[(mt * 16 + lo) * 72 + kk * 32 + hi * 8];
                cu[mt] = __builtin_amdgcn_mfma_f32_16x16x32_bf16(af, ufr[kk], cu[mt], 0, 0, 0);
                cv[mt] = __builtin_amdgcn_mfma_f32_16x16x32_bf16(af, vfr[kk], cv[mt], 0, 0, 0);
            }
        }

        f32x4 inn[2];
        #pragma unroll
        for (int nt = 0; nt < 2; nt++) {
            #pragma unroll
            for (int r = 0; r < 4; r++) {
                float vs = 0.f, ii = 0.f;
                #pragma unroll
                for (int d = 0; d < 3; d++) {
                    float a = cu[d * 2 + nt][r], b = cv[d * 2 + nt][r];
                    vs = fmaf(b, b, vs);
                    ii = fmaf(a, b, ii);
                }
                inn[nt][r] = ii;
                int nl = nt * 16 + hi * 4 + r;
                xlds[nl * 136 + 64 + w * 16 + lo] = f2bf(vs);
            }
        }
        __syncthreads();

        f32x4 c2[2];
        c2[0] = (f32x4)0.0f; c2[1] = (f32x4)0.0f;
        #pragma unroll
        for (int kk = 0; kk < 4; kk++) {
            #pragma unroll
            for (int mt = 0; mt < 2; mt++) {
                bf16x8 af = *(const bf16x8*)&xlds[(mt * 16 + lo) * 136 + kk * 32 + hi * 8];
                c2[mt] = __builtin_amdgcn_mfma_f32_16x16x32_bf16(af, w1fr[kk], c2[mt], 0, 0, 0);
            }
        }
        #pragma unroll
        for (int mt = 0; mt < 2; mt++)
            #pragma unroll
            for (int r = 0; r < 4; r++) {
                float hv = ssp_f(c2[mt][r] + ab1c);
                hlds[(mt * 16 + hi * 4 + r) * 72 + w * 16 + lo] = f2bf(hv);
            }
        __syncthreads();

        f32x4 c3[2][3];
        #pragma unroll
        for (int mt = 0; mt < 2; mt++)
            #pragma unroll
            for (int p = 0; p < 3; p++) c3[mt][p] = (f32x4)0.0f;
        #pragma unroll
        for (int kk = 0; kk < 2; kk++) {
            #pragma unroll
            for (int mt = 0; mt < 2; mt++) {
                bf16x8 af = *(const bf16x8*)&hlds[(mt * 16 + lo) * 72 + kk * 32 + hi * 8];
                #pragma unroll
                for (int p = 0; p < 3; p++)
                    c3[mt][p] = __builtin_amdgcn_mfma_f32_16x16x32_bf16(af, w2fr[p][kk], c3[mt][p], 0, 0, 0);
            }
        }

        // epilogue: s_new/v_new kept in registers only (no global writeback)
        float snew[2][4];
        float vnk[2][4][3];
        #pragma unroll
        for (int mt = 0; mt < 2; mt++) {
            #pragma unroll
            for (int r = 0; r < 4; r++) {
                int n = n0 + mt * 16 + hi * 4 + r;
                if (n >= N) {
                    snew[mt][r] = 0.f;
                    vnk[mt][r][0] = vnk[mt][r][1] = vnk[mt][r][2] = 0.f;
                    continue;
                }
                float a_ss = c3[mt][0][r] + ab2c0;
                float a_sv = c3[mt][1][r] + ab2c1;
                float a_vv = c3[mt][2][r] + ab2c2;
                size_t si = (size_t)n * 64 + g;
                snew[mt][r] = s[si] + a_ss + a_sv * inn[mt][r];
                #pragma unroll
                for (int d = 0; d < 3; d++) {
                    size_t vi = ((size_t)n * 3 + d) * 64 + g;
                    float vold = bf_lo((unsigned)vb[vi]);
                    vnk[mt][r][d] = vold + a_vv * cu[d * 2 + mt][r];
                }
            }
        }

        // ---- heads: eps via MFMA on s_new ----
        __syncthreads();   // hlds free (GEMM3 done by all waves)
        #pragma unroll
        for (int mt = 0; mt < 2; mt++)
            #pragma unroll
            for (int r = 0; r < 4; r++)
                hlds[(mt * 16 + hi * 4 + r) * 72 + g] = f2bf(snew[mt][r]);
        __syncthreads();

        {
            const int a2 = w >> 1;
            f32x4 cx = (f32x4)0.0f;
            #pragma unroll
            for (int kk = 0; kk < 2; kk++) {
                bf16x8 af = *(const bf16x8*)&hlds[(a2 * 16 + lo) * 72 + kk * 32 + hi * 8];
                cx = __builtin_amdgcn_mfma_f32_16x16x32_bf16(af, e1fr[kk], cx, 0, 0, 0);
            }
            float part[4];
            #pragma unroll
            for (int r = 0; r < 4; r++)
                part[r] = ssp_f(cx[r] + eb1v) * ew2v;
            #pragma unroll
            for (int m2 = 1; m2 < 16; m2 <<= 1)
                #pragma unroll
                for (int r = 0; r < 4; r++)
                    part[r] += __shfl_xor(part[r], m2);
            if (lo == 0)
                #pragma unroll
                for (int r = 0; r < 4; r++)
                    epsb[a2][w & 1][hi * 4 + r] = part[r];
        }

        // ---- heads: dipole partials from v_new registers ----
        #pragma unroll
        for (int mt = 0; mt < 2; mt++)
            #pragma unroll
            for (int r = 0; r < 4; r++)
                #pragma unroll
                for (int d = 0; d < 3; d++) {
                    float val = dwv * vnk[mt][r][d];
                    #pragma unroll
                    for (int m2 = 1; m2 < 16; m2 <<= 1)
                        val += __shfl_xor(val, m2);
                    if (lo == 0) dmub[w][mt][hi * 4 + r][d] = val;
                }
        __syncthreads();

        // ---- combine + contention-free per-node stores ----
        if (tid < 32) {
            int nn = tid, a2 = nn >> 4, idx = nn & 15;
            int n = n0 + nn;
            if (n < N)
                epsN[n] = epsb[a2][0][idx] + epsb[a2][1][idx] + eb2c;
        } else if (tid >= 64 && tid < 160) {
            int t2 = tid - 64;
            int nn = t2 / 3, d = t2 % 3;
            int n = n0 + nn;
            if (n < N)
                muN[(size_t)d * N + n] =
                      dmub[0][nn >> 4][nn & 15][d] + dmub[1][nn >> 4][nn & 15][d]
                    + dmub[2][nn >> 4][nn & 15][d] + dmub[3][nn >> 4][nn & 15][d];
        }
    }
}

// ---------- heads reduction: LDS-accumulated, block-level atomics ----------
__global__ void k_heads_red(const float* __restrict__ epsN, const float* __restrict__ muN,
                            const int* __restrict__ bidx,
                            float* __restrict__ eacc, float* __restrict__ macc) {
    __shared__ float se[B];
    __shared__ float sm[3][B];
    if (threadIdx.x < B) se[threadIdx.x] = 0.0f;
    if (threadIdx.x < 3 * B) sm[threadIdx.x >> 6][threadIdx.x & 63] = 0.0f;
    __syncthreads();
    int n = blockIdx.x * blockDim.x + threadIdx.x;
    if (n < N) {
        int b = bidx[n];
        atomicAdd(&se[b], epsN[n]);
        #pragma unroll
        for (int d = 0; d < 3; d++)
            atomicAdd(&sm[d][b], muN[(size_t)d * N + n]);
    }
    __syncthreads();
    if (threadIdx.x < B) atomicAdd(&eacc[threadIdx.x], se[threadIdx.x]);
    if (threadIdx.x >= B && threadIdx.x < 4 * B) {
        int d = (threadIdx.x >> 6) - 1, b = threadIdx.x & 63;
        atomicAdd(&macc[d * B + b], sm[d][b]);
    }
}

__global__ void k_final(const float* __restrict__ eacc, const float* __restrict__ macc,
                        float* __restrict__ out) {
    int b = threadIdx.x;
    if (b < B) {
        out[b] = eacc[b];
        float mx = macc[b], my = macc[B + b], mz = macc[2 * B + b];
        out[B + b] = sqrtf(mx * mx + my * my + mz * mz);
    }
}

extern "C" void kernel_launch(void* const* d_in, const int* in_sizes, int n_in,
                              void* d_out, int out_size, void* d_ws, size_t ws_size,
                              hipStream_t stream) {
    const int*   z     = (const int*)d_in[0];
    const float* pos   = (const float*)d_in[1];
    const int*   ei    = (const int*)d_in[2];
    const int*   bidx  = (const int*)d_in[3];
    const float* emb   = (const float*)d_in[4];
    const float* phi_W = (const float*)d_in[5];
    const float* phi_b = (const float*)d_in[6];
    const float* fW1   = (const float*)d_in[7];
    const float* fb1   = (const float*)d_in[8];
    const float* fW2   = (const float*)d_in[9];
    const float* fb2   = (const float*)d_in[10];
    const float* U_W   = (const float*)d_in[11];
    const float* V_W   = (const float*)d_in[12];
    const float* aW1   = (const float*)d_in[13];
    const float* ab1   = (const float*)d_in[14];
    const float* aW2   = (const float*)d_in[15];
    const float* ab2   = (const float*)d_in[16];
    const float* eW1   = (const float*)d_in[17];
    const float* eb1   = (const float*)d_in[18];
    const float* eW2   = (const float*)d_in[19];
    const float* eb2   = (const float*)d_in[20];
    const float* dip_w = (const float*)d_in[21];
    float* out = (float*)d_out;

    // ---- workspace carve-up ----
    float* ws = (float*)d_ws;
    float* s    = ws;                                  // N*64 f32
    unsigned short* vb = (unsigned short*)(s + (size_t)N * F);  // N*192 bf16
    unsigned* ndA0 = (unsigned*)(vb + (size_t)N * 192);   // N*64 uint (L0 record)
    unsigned* ndAV = ndA0 + (size_t)N * 64;            // N*64*3 uint (L1 fused record)
    unsigned short* Tp = (unsigned short*)(ndAV + (size_t)N * 64 * 3); // NL*TENTA*256 u16
    float* eacc = (float*)(Tp + (size_t)NL * TENTA * 256); // B
    float* macc = eacc + B;                            // 3B
    float* epsN = macc + 3 * B;                        // N
    float* muN  = epsN + N;                            // 3N
    int*   cnt  = (int*)(muN + 3 * (size_t)N);         // N
    int*   off  = cnt  + N;                            // N+1
    int*   cur  = off  + N + 1;                        // N
    int*   bsum = cur  + N;                            // 256
    int*   bpre = bsum + 256;                          // 256
    uint4* edata = (uint4*)(((uintptr_t)(bpre + 256) + 15) & ~(uintptr_t)15); // (E+N)*16B

    hipMemsetAsync(cnt,  0, sizeof(int) * N, stream);
    hipMemsetAsync(eacc, 0, sizeof(float) * 4 * B, stream);
    hipMemsetAsync(out + 2 * B, 0, sizeof(float) * (size_t)N, stream); // charges

    k_hist<<<(E + 255) / 256, 256, 0, stream>>>(ei, cnt);
    k_scan_a<<<NBLK_SCAN, 256, 0, stream>>>(cnt, bsum);
    k_scan_b<<<1, 256, 0, stream>>>(bsum, bpre, off + N);
    k_scan_c<<<NBLK_SCAN, 256, 0, stream>>>(cnt, bpre, off, cur, edata);
    k_scatter<<<(E + 255) / 256, 256, 0, stream>>>(ei, cur, pos, edata);
    k_table<<<(NL * (NB + 1) + 3) / 4, 256, 0, stream>>>(fW1, fb1, fW2, fb2, Tp);

    const int gblocks = (N + 1) / 2;
    const int ublocks = (N + 63) / 64;
    // layer 0
    k_pack0<<<512, 256, 0, stream>>>(s, z, emb, phi_W, phi_b, ndA0);
    k_gather<false><<<gblocks, 128, 0, stream>>>(edata, off, Tp, ndA0, ndAV, s, vb);
    k_update_mfma<<<ublocks, 256, 0, stream>>>(s, vb,
        U_W, V_W, aW1, ab1, aW2, ab2,
        phi_W + (size_t)192 * 64, phi_b + 192, ndAV);
    // layer 1 (update fused with heads; per-node stores, no s/v writeback)
    k_gather<true><<<gblocks, 128, 0, stream>>>(edata, off,
        Tp + (size_t)TENTA * 256, ndA0, ndAV, s, vb);
    k_update_heads<<<ublocks, 256, 0, stream>>>(s, vb,
        U_W + 4096, V_W + 4096, aW1 + 8192, ab1 + F, aW2 + 12288, ab2 + 192,
        eW1, eb1, eW2, eb2, dip_w, epsN, muN);
    k_heads_red<<<(N + 255) / 256, 256, 0, stream>>>(epsN, muN, bidx, eacc, macc);

    k_final<<<1, 64, 0, stream>>>(eacc, macc, out);
}